// Round 3
// baseline (4294.057 us; speedup 1.0000x reference)
//
#include <hip/hip_runtime.h>
#include <math.h>

// VDP ViT attention block, fp32 baseline (correctness-first).
// Shapes: B=8 S=512 E=768 H=12 D=64. N = B*S = 4096 rows.
// ws layout (floats): 8 x N*E buffers (mu_q,sg_q,mu_k,sg_k,mu_v,sg_v,mu_att,sg_att)
// + 4 x N row stats (xx, ss, xx2, ss2)  => ~100.7 MB
constexpr int E = 768;
constexpr int H = 12;
constexpr int D = 64;
constexpr int Bsz = 8;
constexpr int S = 512;
constexpr int NROWS = Bsz * S;           // 4096
constexpr float LOG_PV_M1 = -5.605170185988091f;  // ln(0.01) - 1
constexpr float INV_PV = 100.0f;                  // 1/PRIOR_VAR

__device__ __forceinline__ float softplusf(float x) {
    return fmaxf(x, 0.f) + log1pf(expf(-fabsf(x)));
}

// ---------------- KL ----------------
__global__ void zero_kernel(float* p) { if (threadIdx.x == 0) p[0] = 0.f; }

__global__ __launch_bounds__(256) void kl_kernel(const float* __restrict__ wmu,
                                                 const float* __restrict__ wsig,
                                                 float* __restrict__ out) {
    int tid = blockIdx.x * 256 + threadIdx.x;
    int nthr = gridDim.x * 256;
    float partial = 0.f;
    for (int i = tid; i < E * E; i += nthr) {
        float w = wmu[i];
        partial += w * w;
    }
    partial *= INV_PV;
    if (tid < E) {
        float ws = wsig[tid];
        partial += (float)E * (LOG_PV_M1 - ws + softplusf(ws) * INV_PV);
    }
    __shared__ float red[256];
    red[threadIdx.x] = partial;
    __syncthreads();
    for (int s = 128; s > 0; s >>= 1) {
        if (threadIdx.x < s) red[threadIdx.x] += red[threadIdx.x + s];
        __syncthreads();
    }
    if (threadIdx.x == 0)
        atomicAdd(out, 0.5f * red[0] / (float)(E * E));
}

// ---------------- row stats: xx = sum(mu^2)/E^2, ss = sum(sigma) ----------------
__global__ __launch_bounds__(256) void rowstats_kernel(const float* __restrict__ mu,
                                                       const float* __restrict__ sg,
                                                       float* __restrict__ xx,
                                                       float* __restrict__ ss) {
    int wave = threadIdx.x >> 6, lane = threadIdx.x & 63;
    int row = blockIdx.x * 4 + wave;
    const float* mrow = mu + (size_t)row * E;
    const float* srow = sg + (size_t)row * E;
    float s2 = 0.f, s1 = 0.f;
    for (int i = lane; i < E; i += 64) {
        float m = mrow[i];
        s2 += m * m;
        s1 += srow[i];
    }
    for (int off = 32; off > 0; off >>= 1) {
        s2 += __shfl_xor(s2, off);
        s1 += __shfl_xor(s1, off);
    }
    if (lane == 0) {
        xx[row] = s2 * (1.f / ((float)E * (float)E));
        ss[row] = s1;
    }
}

// ---------------- dual GEMM linear: mu_out = A_mu @ Wmu ; Sigma path fused ----------------
// tile 64x64, BK=16, 256 threads, 4x4 per-thread per GEMM
__global__ __launch_bounds__(256) void linear_kernel(
    const float* __restrict__ Amu, const float* __restrict__ Asg,
    const float* __restrict__ Wmu, const float* __restrict__ wsig,
    const float* __restrict__ xx, const float* __restrict__ ss,
    float* __restrict__ Cmu, float* __restrict__ Csg) {
    constexpr int BK = 16;
    constexpr int PAD = 68;   // stride 68 floats: 272B, 16B-aligned rows, balanced banks
    __shared__ float As_mu[BK][PAD], As_sg[BK][PAD], Bs_mu[BK][PAD], Bs_sg[BK][PAD];
    const int m0 = blockIdx.x * 64;
    const int n0 = blockIdx.y * 64;
    const int t = threadIdx.x;
    const int tr = t >> 4, tc = t & 15;
    float accm[4][4] = {{0.f}}, accs[4][4] = {{0.f}};

    for (int k0 = 0; k0 < E; k0 += BK) {
        __syncthreads();
        {
            // A tiles: 64 rows x 16 k as float4
            int row = t >> 2, kq = (t & 3) << 2;
            float am[4], as[4];
            *(float4*)am = *(const float4*)&Amu[(size_t)(m0 + row) * E + k0 + kq];
            *(float4*)as = *(const float4*)&Asg[(size_t)(m0 + row) * E + k0 + kq];
#pragma unroll
            for (int c = 0; c < 4; ++c) {
                As_mu[kq + c][row] = am[c];
                As_sg[kq + c][row] = as[c];
            }
            // B tile: 16 k x 64 n as float4; sigma-B = wmu^2/768
            int kk = t >> 4, nc = (t & 15) << 2;
            float bm[4];
            *(float4*)bm = *(const float4*)&Wmu[(size_t)(k0 + kk) * E + n0 + nc];
            *(float4*)&Bs_mu[kk][nc] = *(const float4*)bm;
            float bs[4];
#pragma unroll
            for (int c = 0; c < 4; ++c) bs[c] = bm[c] * bm[c] * (1.f / 768.f);
            *(float4*)&Bs_sg[kk][nc] = *(const float4*)bs;
        }
        __syncthreads();
#pragma unroll
        for (int kk = 0; kk < BK; ++kk) {
            float am[4], as[4], bm[4], bs[4];
            *(float4*)am = *(const float4*)&As_mu[kk][tr * 4];
            *(float4*)as = *(const float4*)&As_sg[kk][tr * 4];
            *(float4*)bm = *(const float4*)&Bs_mu[kk][tc * 4];
            *(float4*)bs = *(const float4*)&Bs_sg[kk][tc * 4];
#pragma unroll
            for (int i = 0; i < 4; ++i)
#pragma unroll
                for (int j = 0; j < 4; ++j) {
                    accm[i][j] += am[i] * bm[j];
                    accs[i][j] += as[i] * bs[j];
                }
        }
    }
    // epilogue
#pragma unroll
    for (int j = 0; j < 4; ++j) {
        int n = n0 + tc * 4 + j;
        float WS = softplusf(wsig[n]);
#pragma unroll
        for (int i = 0; i < 4; ++i) {
            int m = m0 + tr * 4 + i;
            Cmu[(size_t)m * E + n] = accm[i][j];
            float sg = accs[i][j] + xx[m] * WS + ss[m] * WS * (1.f / 768.f);
            Csg[(size_t)m * E + n] = softplusf(sg);
        }
    }
}

// ---------------- fused attention per (b, h, 32-row q tile) ----------------
__global__ __launch_bounds__(512) void attn_kernel(
    const float* __restrict__ mu_q, const float* __restrict__ sg_q,
    const float* __restrict__ mu_k, const float* __restrict__ sg_k,
    const float* __restrict__ mu_v, const float* __restrict__ sg_v,
    float* __restrict__ mu_o, float* __restrict__ sg_o) {
    constexpr int QB = 32, CH = 64, PAD = 68;
    __shared__ float q_mu[QB][PAD];   // mu_q at q rows
    __shared__ float q_cb[QB][PAD];   // (mu_q^2 + sg_q)/64 at q rows  (a + c terms combined)
    __shared__ float k_q2[QB][PAD];   // mu_k^2/64 at q rows           (transposed b term)
    __shared__ float bufA[CH][PAD], bufB[CH][PAD], bufC[CH][PAD];
    __shared__ float w_m[QB][PAD], w_s[QB][PAD];

    const int bid = blockIdx.x;
    const int b = bid / (H * (S / QB));
    const int rem = bid % (H * (S / QB));
    const int h = rem / (S / QB);
    const int qt = rem % (S / QB);
    const int q0 = qt * QB;
    const int t = threadIdx.x;
    const int lane = t & 63, wid = t >> 6;  // 8 waves
    const size_t base = ((size_t)b * S) * E + h * D;

    // resident q-side tiles
    for (int i = t; i < QB * D; i += 512) {
        int r = i >> 6, d = i & 63;
        size_t g = base + (size_t)(q0 + r) * E + d;
        float qm = mu_q[g], qs = sg_q[g], km = mu_k[g];
        q_mu[r][d] = qm;
        q_cb[r][d] = (qm * qm + qs) * (1.f / 64.f);
        k_q2[r][d] = km * km * (1.f / 64.f);
    }

    // ---- pass 1: softmax stats over mu_score/8 ----
    float mrow[4], zrow[4];
#pragma unroll
    for (int i = 0; i < 4; ++i) { mrow[i] = -1e30f; zrow[i] = 0.f; }
    for (int c = 0; c < S / CH; ++c) {
        __syncthreads();
        for (int i = t; i < CH * D; i += 512) {
            int r = i >> 6, d = i & 63;
            bufA[r][d] = mu_k[base + (size_t)(c * CH + r) * E + d];
        }
        __syncthreads();
#pragma unroll
        for (int ri = 0; ri < 4; ++ri) {
            int r = wid + ri * 8;
            float s = 0.f;
#pragma unroll
            for (int d4 = 0; d4 < D; d4 += 4) {
                float a[4], kk[4];
                *(float4*)a = *(const float4*)&q_mu[r][d4];
                *(float4*)kk = *(const float4*)&bufA[lane][d4];
                s += a[0] * kk[0] + a[1] * kk[1] + a[2] * kk[2] + a[3] * kk[3];
            }
            s *= 0.125f;
            float cm = s;
            for (int off = 32; off > 0; off >>= 1) cm = fmaxf(cm, __shfl_xor(cm, off));
            float nm = fmaxf(mrow[ri], cm);
            float cz = __expf(s - nm);
            for (int off = 32; off > 0; off >>= 1) cz += __shfl_xor(cz, off);
            zrow[ri] = zrow[ri] * __expf(mrow[ri] - nm) + cz;
            mrow[ri] = nm;
        }
    }
    float zinv[4];
#pragma unroll
    for (int i = 0; i < 4; ++i) zinv[i] = 1.f / zrow[i];

    // ---- pass 2: exact weights + PV accumulation ----
    float accm[4] = {0.f}, accd[4] = {0.f}, acce[4] = {0.f}, accf[4] = {0.f};
    for (int c = 0; c < S / CH; ++c) {
        __syncthreads();
        for (int i = t; i < CH * D; i += 512) {
            int r = i >> 6, d = i & 63;
            size_t g = base + (size_t)(c * CH + r) * E + d;
            bufA[r][d] = mu_k[g];
            bufB[r][d] = sg_k[g];
            bufC[r][d] = sg_q[g];
        }
        __syncthreads();
#pragma unroll
        for (int ri = 0; ri < 4; ++ri) {
            int r = wid + ri * 8;
            float sm = 0.f, sv = 0.f;
#pragma unroll
            for (int d4 = 0; d4 < D; d4 += 4) {
                float qm[4], qc[4], k2[4], km[4], ks[4], qk[4];
                *(float4*)qm = *(const float4*)&q_mu[r][d4];
                *(float4*)qc = *(const float4*)&q_cb[r][d4];
                *(float4*)k2 = *(const float4*)&k_q2[r][d4];
                *(float4*)km = *(const float4*)&bufA[lane][d4];
                *(float4*)ks = *(const float4*)&bufB[lane][d4];
                *(float4*)qk = *(const float4*)&bufC[lane][d4];
#pragma unroll
                for (int u = 0; u < 4; ++u) {
                    sm += qm[u] * km[u];
                    sv += qc[u] * ks[u] + k2[u] * qk[u];
                }
            }
            float mu_s = sm * 0.125f;          // /sqrt(64)
            float sg_s = sv * (1.f / 64.f);    // /64
            float w = __expf(mu_s - mrow[ri]) * zinv[ri];
            float g1 = w - w * w;
            float Sw = g1 * g1 * sg_s * (1.f / 512.f);
            w_m[r][lane] = w;
            w_s[r][lane] = Sw;
        }
        __syncthreads();
        for (int i = t; i < CH * D; i += 512) {
            int r = i >> 6, d = i & 63;
            size_t g = base + (size_t)(c * CH + r) * E + d;
            float vm = mu_v[g], vs = sg_v[g];
            bufA[r][d] = vm;
            bufB[r][d] = vs;
            bufC[r][d] = vm * vm;
        }
        __syncthreads();
        for (int kj = 0; kj < CH; ++kj) {
            float vm = bufA[kj][lane], vs = bufB[kj][lane], v2 = bufC[kj][lane];
#pragma unroll
            for (int ri = 0; ri < 4; ++ri) {
                int r = wid + ri * 8;
                float w = w_m[r][kj];
                float Sw = w_s[r][kj];
                accm[ri] += w * vm;
                accd[ri] += w * w * vs;
                acce[ri] += Sw * v2;
                accf[ri] += Sw * vs;
            }
        }
    }
    // epilogue: d,e,f all carry a 1/512 factor
#pragma unroll
    for (int ri = 0; ri < 4; ++ri) {
        int r = wid + ri * 8;
        size_t g = base + (size_t)(q0 + r) * E + lane;
        mu_o[g] = accm[ri];
        sg_o[g] = softplusf((accd[ri] + acce[ri] + accf[ri]) * (1.f / 512.f));
    }
}

// ---------------- launch ----------------
extern "C" void kernel_launch(void* const* d_in, const int* in_sizes, int n_in,
                              void* d_out, int out_size, void* d_ws, size_t ws_size,
                              hipStream_t stream) {
    const float* mu_in = (const float*)d_in[0];
    const float* sg_in = (const float*)d_in[1];
    const float* wq_mu = (const float*)d_in[2];
    const float* wq_sg = (const float*)d_in[3];
    const float* wk_mu = (const float*)d_in[4];
    const float* wk_sg = (const float*)d_in[5];
    const float* wv_mu = (const float*)d_in[6];
    const float* wv_sg = (const float*)d_in[7];
    const float* wo_mu = (const float*)d_in[8];
    const float* wo_sg = (const float*)d_in[9];

    float* out_mu = (float*)d_out;                      // [4096,768]
    float* out_sg = out_mu + (size_t)NROWS * E;         // [4096,768]
    float* out_kl = out_sg + (size_t)NROWS * E;         // scalar

    const size_t NE = (size_t)NROWS * E;
    float* ws = (float*)d_ws;
    float* mu_q = ws;
    float* sg_q = ws + NE;
    float* mu_k = ws + 2 * NE;
    float* sg_k = ws + 3 * NE;
    float* mu_v = ws + 4 * NE;
    float* sg_v = ws + 5 * NE;
    float* mu_a = ws + 6 * NE;
    float* sg_a = ws + 7 * NE;
    float* xx = ws + 8 * NE;
    float* ss = xx + NROWS;
    float* xx2 = ss + NROWS;
    float* ss2 = xx2 + NROWS;

    // KL
    zero_kernel<<<1, 64, 0, stream>>>(out_kl);
    kl_kernel<<<64, 256, 0, stream>>>(wq_mu, wq_sg, out_kl);
    kl_kernel<<<64, 256, 0, stream>>>(wk_mu, wk_sg, out_kl);
    kl_kernel<<<64, 256, 0, stream>>>(wv_mu, wv_sg, out_kl);
    kl_kernel<<<64, 256, 0, stream>>>(wo_mu, wo_sg, out_kl);

    // shared input row stats
    rowstats_kernel<<<NROWS / 4, 256, 0, stream>>>(mu_in, sg_in, xx, ss);

    // Q, K, V linears
    dim3 ggrid(NROWS / 64, E / 64);
    linear_kernel<<<ggrid, 256, 0, stream>>>(mu_in, sg_in, wq_mu, wq_sg, xx, ss, mu_q, sg_q);
    linear_kernel<<<ggrid, 256, 0, stream>>>(mu_in, sg_in, wk_mu, wk_sg, xx, ss, mu_k, sg_k);
    linear_kernel<<<ggrid, 256, 0, stream>>>(mu_in, sg_in, wv_mu, wv_sg, xx, ss, mu_v, sg_v);

    // attention
    attn_kernel<<<Bsz * H * (S / 32), 512, 0, stream>>>(mu_q, sg_q, mu_k, sg_k,
                                                        mu_v, sg_v, mu_a, sg_a);

    // output linear
    rowstats_kernel<<<NROWS / 4, 256, 0, stream>>>(mu_a, sg_a, xx2, ss2);
    linear_kernel<<<ggrid, 256, 0, stream>>>(mu_a, sg_a, wo_mu, wo_sg, xx2, ss2, out_mu, out_sg);
}

// Round 8
// 540.353 us; speedup vs baseline: 7.9468x; 7.9468x over previous
//
#include <hip/hip_runtime.h>
#include <math.h>

// VDP ViT attention block. R6: MFMA attention (split-bf16 scores) + MFMA bf16 linears.
constexpr int E = 768;
constexpr int H = 12;
constexpr int D = 64;
constexpr int Bsz = 8;
constexpr int S = 512;
constexpr int NROWS = Bsz * S;           // 4096
constexpr float LOG_PV_M1 = -5.605170185988091f;  // ln(0.01) - 1
constexpr float INV_PV = 100.0f;                  // 1/PRIOR_VAR

typedef __attribute__((ext_vector_type(8))) short short8;
typedef __attribute__((ext_vector_type(4))) float floatx4;

__device__ __forceinline__ float softplusf(float x) {
    return fmaxf(x, 0.f) + log1pf(expf(-fabsf(x)));
}
__device__ __forceinline__ unsigned short f2bf(float f) {
    unsigned int u = __float_as_uint(f);
    unsigned int r = (u + 0x7fffu + ((u >> 16) & 1u)) >> 16;
    return (unsigned short)r;
}
__device__ __forceinline__ float bf2f(unsigned short h) {
    return __uint_as_float(((unsigned int)h) << 16);
}
__device__ __forceinline__ unsigned int pack2(float a, float b) {
    return (unsigned int)f2bf(a) | ((unsigned int)f2bf(b) << 16);
}
__device__ __forceinline__ void split2(float a, float b, unsigned int& hi, unsigned int& lo) {
    unsigned short ha = f2bf(a), hb = f2bf(b);
    hi = (unsigned int)ha | ((unsigned int)hb << 16);
    lo = (unsigned int)f2bf(a - bf2f(ha)) | ((unsigned int)f2bf(b - bf2f(hb)) << 16);
}

// ---------------- KL ----------------
__global__ void zero_kernel(float* p) { if (threadIdx.x == 0) p[0] = 0.f; }

__global__ __launch_bounds__(256) void kl_kernel(const float* __restrict__ wmu,
                                                 const float* __restrict__ wsig,
                                                 float* __restrict__ out) {
    int tid = blockIdx.x * 256 + threadIdx.x;
    int nthr = gridDim.x * 256;
    float partial = 0.f;
    for (int i = tid; i < E * E; i += nthr) {
        float w = wmu[i];
        partial += w * w;
    }
    partial *= INV_PV;
    if (tid < E) {
        float ws = wsig[tid];
        partial += (float)E * (LOG_PV_M1 - ws + softplusf(ws) * INV_PV);
    }
    __shared__ float red[256];
    red[threadIdx.x] = partial;
    __syncthreads();
    for (int s = 128; s > 0; s >>= 1) {
        if (threadIdx.x < s) red[threadIdx.x] += red[threadIdx.x + s];
        __syncthreads();
    }
    if (threadIdx.x == 0)
        atomicAdd(out, 0.5f * red[0] / (float)(E * E));
}

// ---------------- row stats ----------------
__global__ __launch_bounds__(256) void rowstats_kernel(const float* __restrict__ mu,
                                                       const float* __restrict__ sg,
                                                       float* __restrict__ xx,
                                                       float* __restrict__ ss) {
    int wave = threadIdx.x >> 6, lane = threadIdx.x & 63;
    int row = blockIdx.x * 4 + wave;
    const float* mrow = mu + (size_t)row * E;
    const float* srow = sg + (size_t)row * E;
    float s2 = 0.f, s1 = 0.f;
    for (int i = lane; i < E; i += 64) {
        float m = mrow[i];
        s2 += m * m;
        s1 += srow[i];
    }
    for (int off = 32; off > 0; off >>= 1) {
        s2 += __shfl_xor(s2, off);
        s1 += __shfl_xor(s1, off);
    }
    if (lane == 0) {
        xx[row] = s2 * (1.f / ((float)E * (float)E));
        ss[row] = s1;
    }
}

// ---------------- MFMA dual-GEMM linear ----------------
// BM=64 BN=128 BK=32, 512 threads = 8 waves: qsub=wid>>1 (16-row M-subtile),
// c2=wid&1 (64-col N-half), 4 N-frags per wave. Plain bf16, fp32 accumulate.
// A staged row-major [64][40]; W staged TRANSPOSED [128][40] (col-major k-packed,
// same pattern as attention's vT staging). Epilogue fuses softplus + rank-1 terms.
__global__ __launch_bounds__(512, 1) void linear_mfma_kernel(
    const float* __restrict__ Amu, const float* __restrict__ Asg,
    const float* __restrict__ Wmu, const float* __restrict__ wsig,
    const float* __restrict__ xx, const float* __restrict__ ss,
    float* __restrict__ Cmu, float* __restrict__ Csg) {
    constexpr int BM = 64, BN = 128, BK = 32, LDK = 40;
    __shared__ unsigned short A_mu[BM][LDK], A_sg[BM][LDK];
    __shared__ unsigned short W_mu[BN][LDK], W_sg[BN][LDK];
    const int m0 = blockIdx.x * BM;
    const int n0 = blockIdx.y * BN;
    const int t = threadIdx.x;
    const int lane = t & 63, wid = t >> 6;
    const int qsub = wid >> 1, c2 = wid & 1;
    const int lr = lane & 15, lg = lane >> 4;

    floatx4 accm[4] = {{0.f,0.f,0.f,0.f},{0.f,0.f,0.f,0.f},{0.f,0.f,0.f,0.f},{0.f,0.f,0.f,0.f}};
    floatx4 accs[4] = {{0.f,0.f,0.f,0.f},{0.f,0.f,0.f,0.f},{0.f,0.f,0.f,0.f},{0.f,0.f,0.f,0.f}};

    for (int k0 = 0; k0 < E; k0 += BK) {
        __syncthreads();
        {   // A stage: 64 rows x 32 k
            int r = t >> 3, g = (t & 7) * 4;
            float4 am = *(const float4*)&Amu[(size_t)(m0 + r) * E + k0 + g];
            float4 as = *(const float4*)&Asg[(size_t)(m0 + r) * E + k0 + g];
            *(uint2*)&A_mu[r][g] = make_uint2(pack2(am.x, am.y), pack2(am.z, am.w));
            *(uint2*)&A_sg[r][g] = make_uint2(pack2(as.x, as.y), pack2(as.z, as.w));
        }
        {   // W stage transposed: thread -> k pair (2kp,2kp+1), n = n4..n4+3
            int kp = t & 15, n4 = (t >> 4) * 4;
            const float* p0 = &Wmu[(size_t)(k0 + 2 * kp) * E + n0 + n4];
            const float* p1 = p0 + E;
            float4 w0 = *(const float4*)p0, w1 = *(const float4*)p1;
            *(unsigned int*)&W_mu[n4 + 0][2 * kp] = pack2(w0.x, w1.x);
            *(unsigned int*)&W_mu[n4 + 1][2 * kp] = pack2(w0.y, w1.y);
            *(unsigned int*)&W_mu[n4 + 2][2 * kp] = pack2(w0.z, w1.z);
            *(unsigned int*)&W_mu[n4 + 3][2 * kp] = pack2(w0.w, w1.w);
            const float is = 1.f / 768.f;
            *(unsigned int*)&W_sg[n4 + 0][2 * kp] = pack2(w0.x * w0.x * is, w1.x * w1.x * is);
            *(unsigned int*)&W_sg[n4 + 1][2 * kp] = pack2(w0.y * w0.y * is, w1.y * w1.y * is);
            *(unsigned int*)&W_sg[n4 + 2][2 * kp] = pack2(w0.z * w0.z * is, w1.z * w1.z * is);
            *(unsigned int*)&W_sg[n4 + 3][2 * kp] = pack2(w0.w * w0.w * is, w1.w * w1.w * is);
        }
        __syncthreads();
        short8 a_mu = *(const short8*)&A_mu[qsub * 16 + lr][lg * 8];
        short8 a_sg = *(const short8*)&A_sg[qsub * 16 + lr][lg * 8];
#pragma unroll
        for (int f = 0; f < 4; ++f) {
            int col = c2 * 64 + f * 16 + lr;
            short8 b_mu = *(const short8*)&W_mu[col][lg * 8];
            short8 b_sg = *(const short8*)&W_sg[col][lg * 8];
            accm[f] = __builtin_amdgcn_mfma_f32_16x16x32_bf16(a_mu, b_mu, accm[f], 0, 0, 0);
            accs[f] = __builtin_amdgcn_mfma_f32_16x16x32_bf16(a_sg, b_sg, accs[f], 0, 0, 0);
        }
    }
    // epilogue: C/D frag col=lr, row=4*lg+v
#pragma unroll
    for (int f = 0; f < 4; ++f) {
        int n = n0 + c2 * 64 + f * 16 + lr;
        float WS = softplusf(wsig[n]);
#pragma unroll
        for (int v = 0; v < 4; ++v) {
            int m = m0 + qsub * 16 + lg * 4 + v;
            Cmu[(size_t)m * E + n] = accm[f][v];
            float sg = accs[f][v] + xx[m] * WS + ss[m] * WS * (1.f / 768.f);
            Csg[(size_t)m * E + n] = softplusf(sg);
        }
    }
}

// ---------------- MFMA attention (unchanged from audited R5) ----------------
__global__ __launch_bounds__(512, 1) void attn_mfma_kernel(
    const float* __restrict__ mu_q, const float* __restrict__ sg_q,
    const float* __restrict__ mu_k, const float* __restrict__ sg_k,
    const float* __restrict__ mu_v, const float* __restrict__ sg_v,
    float* __restrict__ mu_o, float* __restrict__ sg_o) {
    constexpr int QB = 64, KC = 64, LDK = 72;
    __shared__ unsigned short q_hi[QB][LDK], q_lo[QB][LDK], q_cb[QB][LDK], q_k2[QB][LDK];
    __shared__ unsigned short k_hi[KC][LDK], k_lo[KC][LDK], k_sg[KC][LDK], k_qsg[KC][LDK];
    __shared__ unsigned short vT_mu[D][LDK], vT_sg[D][LDK], vT_cb[D][LDK];
    __shared__ unsigned short p_w[QB][LDK], p_w2[QB][LDK], p_sw[QB][LDK];
    __shared__ float red_m[2][QB], red_z[2][QB];

    const int bid = blockIdx.x;
    const int qt = bid & 7;
    const int hb = bid >> 3;
    const int h = hb % H;
    const int b = hb / H;
    const int q0 = qt * QB;
    const int t = threadIdx.x;
    const int lane = t & 63, wid = t >> 6;
    const int qsub = wid >> 1, c2 = wid & 1;
    const int Q0 = qsub * 16;
    const int lr = lane & 15, lg = lane >> 4;
    const size_t base = (size_t)b * S * E + (size_t)h * D;

    {
        int r = t >> 3, g = (t & 7) * 8;
        const float* pm = mu_q + base + (size_t)(q0 + r) * E + g;
        const float* ps = sg_q + base + (size_t)(q0 + r) * E + g;
        const float* pk = mu_k + base + (size_t)(q0 + r) * E + g;
        float4 m0 = *(const float4*)pm, m1 = *(const float4*)(pm + 4);
        float4 s0 = *(const float4*)ps, s1 = *(const float4*)(ps + 4);
        float4 k0 = *(const float4*)pk, k1 = *(const float4*)(pk + 4);
        unsigned int h0, l0, h1, l1, h2, l2, h3, l3;
        split2(m0.x, m0.y, h0, l0); split2(m0.z, m0.w, h1, l1);
        split2(m1.x, m1.y, h2, l2); split2(m1.z, m1.w, h3, l3);
        *(uint4*)&q_hi[r][g] = make_uint4(h0, h1, h2, h3);
        *(uint4*)&q_lo[r][g] = make_uint4(l0, l1, l2, l3);
        const float i64 = 1.f / 64.f;
        *(uint4*)&q_cb[r][g] = make_uint4(
            pack2((m0.x * m0.x + s0.x) * i64, (m0.y * m0.y + s0.y) * i64),
            pack2((m0.z * m0.z + s0.z) * i64, (m0.w * m0.w + s0.w) * i64),
            pack2((m1.x * m1.x + s1.x) * i64, (m1.y * m1.y + s1.y) * i64),
            pack2((m1.z * m1.z + s1.z) * i64, (m1.w * m1.w + s1.w) * i64));
        *(uint4*)&q_k2[r][g] = make_uint4(
            pack2(k0.x * k0.x * i64, k0.y * k0.y * i64),
            pack2(k0.z * k0.z * i64, k0.w * k0.w * i64),
            pack2(k1.x * k1.x * i64, k1.y * k1.y * i64),
            pack2(k1.z * k1.z * i64, k1.w * k1.w * i64));
    }

    float mv[4], zv[4];
#pragma unroll
    for (int v = 0; v < 4; ++v) { mv[v] = -1e30f; zv[v] = 0.f; }

    for (int c = 0; c < S / KC; ++c) {
        __syncthreads();
        {
            int r = t >> 3, g = (t & 7) * 8;
            const float* pk = mu_k + base + (size_t)(c * KC + r) * E + g;
            float4 k0 = *(const float4*)pk, k1 = *(const float4*)(pk + 4);
            unsigned int h0, l0, h1, l1, h2, l2, h3, l3;
            split2(k0.x, k0.y, h0, l0); split2(k0.z, k0.w, h1, l1);
            split2(k1.x, k1.y, h2, l2); split2(k1.z, k1.w, h3, l3);
            *(uint4*)&k_hi[r][g] = make_uint4(h0, h1, h2, h3);
            *(uint4*)&k_lo[r][g] = make_uint4(l0, l1, l2, l3);
        }
        __syncthreads();
        floatx4 cm[2] = {{0.f, 0.f, 0.f, 0.f}, {0.f, 0.f, 0.f, 0.f}};
#pragma unroll
        for (int ks = 0; ks < 2; ++ks) {
            int ao = lg * 8 + ks * 32;
            short8 ahi = *(const short8*)&q_hi[Q0 + lr][ao];
            short8 alo = *(const short8*)&q_lo[Q0 + lr][ao];
#pragma unroll
            for (int f = 0; f < 2; ++f) {
                int key = c2 * 32 + f * 16 + lr;
                short8 bhi = *(const short8*)&k_hi[key][ao];
                short8 blo = *(const short8*)&k_lo[key][ao];
                cm[f] = __builtin_amdgcn_mfma_f32_16x16x32_bf16(ahi, bhi, cm[f], 0, 0, 0);
                cm[f] = __builtin_amdgcn_mfma_f32_16x16x32_bf16(ahi, blo, cm[f], 0, 0, 0);
                cm[f] = __builtin_amdgcn_mfma_f32_16x16x32_bf16(alo, bhi, cm[f], 0, 0, 0);
            }
        }
#pragma unroll
        for (int v = 0; v < 4; ++v) {
            float s0 = cm[0][v] * 0.125f, s1 = cm[1][v] * 0.125f;
            float cmx = fmaxf(s0, s1);
            for (int off = 1; off <= 8; off <<= 1) cmx = fmaxf(cmx, __shfl_xor(cmx, off));
            float ez = __expf(s0 - cmx) + __expf(s1 - cmx);
            for (int off = 1; off <= 8; off <<= 1) ez += __shfl_xor(ez, off);
            float nm = fmaxf(mv[v], cmx);
            zv[v] = zv[v] * __expf(mv[v] - nm) + ez * __expf(cmx - nm);
            mv[v] = nm;
        }
    }
    __syncthreads();
    if ((lane & 15) == 0) {
#pragma unroll
        for (int v = 0; v < 4; ++v) {
            int qr = Q0 + lg * 4 + v;
            red_m[c2][qr] = mv[v];
            red_z[c2][qr] = zv[v];
        }
    }
    __syncthreads();
    float fm[4], fzi[4];
#pragma unroll
    for (int v = 0; v < 4; ++v) {
        int qr = Q0 + lg * 4 + v;
        float m0 = red_m[0][qr], m1 = red_m[1][qr];
        float mm = fmaxf(m0, m1);
        float zz = red_z[0][qr] * __expf(m0 - mm) + red_z[1][qr] * __expf(m1 - mm);
        fm[v] = mm;
        fzi[v] = 1.f / zz;
    }

    floatx4 accm[2] = {{0.f, 0.f, 0.f, 0.f}, {0.f, 0.f, 0.f, 0.f}};
    floatx4 accs[2] = {{0.f, 0.f, 0.f, 0.f}, {0.f, 0.f, 0.f, 0.f}};
    for (int c = 0; c < S / KC; ++c) {
        __syncthreads();
        {
            int r = t >> 3, g = (t & 7) * 8;
            const float* pk = mu_k + base + (size_t)(c * KC + r) * E + g;
            const float* pskk = sg_k + base + (size_t)(c * KC + r) * E + g;
            const float* psq = sg_q + base + (size_t)(c * KC + r) * E + g;
            float4 k0 = *(const float4*)pk, k1 = *(const float4*)(pk + 4);
            float4 s0 = *(const float4*)pskk, s1 = *(const float4*)(pskk + 4);
            float4 g0 = *(const float4*)psq, g1 = *(const float4*)(psq + 4);
            unsigned int h0, l0, h1, l1, h2, l2, h3, l3;
            split2(k0.x, k0.y, h0, l0); split2(k0.z, k0.w, h1, l1);
            split2(k1.x, k1.y, h2, l2); split2(k1.z, k1.w, h3, l3);
            *(uint4*)&k_hi[r][g] = make_uint4(h0, h1, h2, h3);
            *(uint4*)&k_lo[r][g] = make_uint4(l0, l1, l2, l3);
            *(uint4*)&k_sg[r][g] = make_uint4(pack2(s0.x, s0.y), pack2(s0.z, s0.w),
                                              pack2(s1.x, s1.y), pack2(s1.z, s1.w));
            *(uint4*)&k_qsg[r][g] = make_uint4(pack2(g0.x, g0.y), pack2(g0.z, g0.w),
                                               pack2(g1.x, g1.y), pack2(g1.z, g1.w));
        }
        {
            int kp = t & 31, dg = (t >> 5) * 4;
            const float* pv0 = mu_v + base + (size_t)(c * KC + 2 * kp) * E + dg;
            const float* pv1 = pv0 + E;
            const float* ps0 = sg_v + base + (size_t)(c * KC + 2 * kp) * E + dg;
            const float* ps1 = ps0 + E;
            float4 a0 = *(const float4*)pv0, a1 = *(const float4*)pv1;
            float4 b0 = *(const float4*)ps0, b1 = *(const float4*)ps1;
            *(unsigned int*)&vT_mu[dg + 0][2 * kp] = pack2(a0.x, a1.x);
            *(unsigned int*)&vT_mu[dg + 1][2 * kp] = pack2(a0.y, a1.y);
            *(unsigned int*)&vT_mu[dg + 2][2 * kp] = pack2(a0.z, a1.z);
            *(unsigned int*)&vT_mu[dg + 3][2 * kp] = pack2(a0.w, a1.w);
            *(unsigned int*)&vT_sg[dg + 0][2 * kp] = pack2(b0.x, b1.x);
            *(unsigned int*)&vT_sg[dg + 1][2 * kp] = pack2(b0.y, b1.y);
            *(unsigned int*)&vT_sg[dg + 2][2 * kp] = pack2(b0.z, b1.z);
            *(unsigned int*)&vT_sg[dg + 3][2 * kp] = pack2(b0.w, b1.w);
            *(unsigned int*)&vT_cb[dg + 0][2 * kp] = pack2(a0.x * a0.x + b0.x, a1.x * a1.x + b1.x);
            *(unsigned int*)&vT_cb[dg + 1][2 * kp] = pack2(a0.y * a0.y + b0.y, a1.y * a1.y + b1.y);
            *(unsigned int*)&vT_cb[dg + 2][2 * kp] = pack2(a0.z * a0.z + b0.z, a1.z * a1.z + b1.z);
            *(unsigned int*)&vT_cb[dg + 3][2 * kp] = pack2(a0.w * a0.w + b0.w, a1.w * a1.w + b1.w);
        }
        __syncthreads();
        floatx4 cm[2] = {{0.f, 0.f, 0.f, 0.f}, {0.f, 0.f, 0.f, 0.f}};
        floatx4 cs[2] = {{0.f, 0.f, 0.f, 0.f}, {0.f, 0.f, 0.f, 0.f}};
#pragma unroll
        for (int ks = 0; ks < 2; ++ks) {
            int ao = lg * 8 + ks * 32;
            short8 ahi = *(const short8*)&q_hi[Q0 + lr][ao];
            short8 alo = *(const short8*)&q_lo[Q0 + lr][ao];
            short8 acb = *(const short8*)&q_cb[Q0 + lr][ao];
            short8 ak2 = *(const short8*)&q_k2[Q0 + lr][ao];
#pragma unroll
            for (int f = 0; f < 2; ++f) {
                int key = c2 * 32 + f * 16 + lr;
                short8 bhi = *(const short8*)&k_hi[key][ao];
                short8 blo = *(const short8*)&k_lo[key][ao];
                short8 bsg = *(const short8*)&k_sg[key][ao];
                short8 bqs = *(const short8*)&k_qsg[key][ao];
                cm[f] = __builtin_amdgcn_mfma_f32_16x16x32_bf16(ahi, bhi, cm[f], 0, 0, 0);
                cm[f] = __builtin_amdgcn_mfma_f32_16x16x32_bf16(ahi, blo, cm[f], 0, 0, 0);
                cm[f] = __builtin_amdgcn_mfma_f32_16x16x32_bf16(alo, bhi, cm[f], 0, 0, 0);
                cs[f] = __builtin_amdgcn_mfma_f32_16x16x32_bf16(acb, bsg, cs[f], 0, 0, 0);
                cs[f] = __builtin_amdgcn_mfma_f32_16x16x32_bf16(ak2, bqs, cs[f], 0, 0, 0);
            }
        }
#pragma unroll
        for (int f = 0; f < 2; ++f)
#pragma unroll
            for (int v = 0; v < 4; ++v) {
                int qr = Q0 + lg * 4 + v;
                int key = c2 * 32 + f * 16 + lr;
                float w = __expf(cm[f][v] * 0.125f - fm[v]) * fzi[v];
                float sgs = cs[f][v] * (1.f / 64.f);
                float g1 = w - w * w;
                p_w[qr][key] = f2bf(w);
                p_w2[qr][key] = f2bf(w * w * (1.f / 512.f));
                p_sw[qr][key] = f2bf(g1 * g1 * sgs * (1.f / 262144.f));  // 1/512^2
            }
        __syncthreads();
#pragma unroll
        for (int ks = 0; ks < 2; ++ks) {
            int ko = lg * 8 + ks * 32;
            short8 aw = *(const short8*)&p_w[Q0 + lr][ko];
            short8 aw2 = *(const short8*)&p_w2[Q0 + lr][ko];
            short8 asw = *(const short8*)&p_sw[Q0 + lr][ko];
#pragma unroll
            for (int nf = 0; nf < 2; ++nf) {
                int dcol = (wid & 1) * 32 + nf * 16 + lr;
                short8 bvm = *(const short8*)&vT_mu[dcol][ko];
                short8 bvs = *(const short8*)&vT_sg[dcol][ko];
                short8 bvc = *(const short8*)&vT_cb[dcol][ko];
                accm[nf] = __builtin_amdgcn_mfma_f32_16x16x32_bf16(aw, bvm, accm[nf], 0, 0, 0);
                accs[nf] = __builtin_amdgcn_mfma_f32_16x16x32_bf16(aw2, bvs, accs[nf], 0, 0, 0);
                accs[nf] = __builtin_amdgcn_mfma_f32_16x16x32_bf16(asw, bvc, accs[nf], 0, 0, 0);
            }
        }
    }
#pragma unroll
    for (int nf = 0; nf < 2; ++nf)
#pragma unroll
        for (int v = 0; v < 4; ++v) {
            int qg = q0 + Q0 + lg * 4 + v;
            int dcol = (wid & 1) * 32 + nf * 16 + lr;
            size_t g = base + (size_t)qg * E + dcol;
            mu_o[g] = accm[nf][v];
            sg_o[g] = softplusf(accs[nf][v]);
        }
}

// ---------------- launch ----------------
extern "C" void kernel_launch(void* const* d_in, const int* in_sizes, int n_in,
                              void* d_out, int out_size, void* d_ws, size_t ws_size,
                              hipStream_t stream) {
    const float* mu_in = (const float*)d_in[0];
    const float* sg_in = (const float*)d_in[1];
    const float* wq_mu = (const float*)d_in[2];
    const float* wq_sg = (const float*)d_in[3];
    const float* wk_mu = (const float*)d_in[4];
    const float* wk_sg = (const float*)d_in[5];
    const float* wv_mu = (const float*)d_in[6];
    const float* wv_sg = (const float*)d_in[7];
    const float* wo_mu = (const float*)d_in[8];
    const float* wo_sg = (const float*)d_in[9];

    float* out_mu = (float*)d_out;
    float* out_sg = out_mu + (size_t)NROWS * E;
    float* out_kl = out_sg + (size_t)NROWS * E;

    const size_t NE = (size_t)NROWS * E;
    float* ws = (float*)d_ws;
    float* mu_q = ws;
    float* sg_q = ws + NE;
    float* mu_k = ws + 2 * NE;
    float* sg_k = ws + 3 * NE;
    float* mu_v = ws + 4 * NE;
    float* sg_v = ws + 5 * NE;
    float* mu_a = ws + 6 * NE;
    float* sg_a = ws + 7 * NE;
    float* xx = ws + 8 * NE;
    float* ss = xx + NROWS;
    float* xx2 = ss + NROWS;
    float* ss2 = xx2 + NROWS;

    zero_kernel<<<1, 64, 0, stream>>>(out_kl);
    kl_kernel<<<64, 256, 0, stream>>>(wq_mu, wq_sg, out_kl);
    kl_kernel<<<64, 256, 0, stream>>>(wk_mu, wk_sg, out_kl);
    kl_kernel<<<64, 256, 0, stream>>>(wv_mu, wv_sg, out_kl);
    kl_kernel<<<64, 256, 0, stream>>>(wo_mu, wo_sg, out_kl);

    rowstats_kernel<<<NROWS / 4, 256, 0, stream>>>(mu_in, sg_in, xx, ss);

    dim3 ggrid(NROWS / 64, E / 128);
    linear_mfma_kernel<<<ggrid, 512, 0, stream>>>(mu_in, sg_in, wq_mu, wq_sg, xx, ss, mu_q, sg_q);
    linear_mfma_kernel<<<ggrid, 512, 0, stream>>>(mu_in, sg_in, wk_mu, wk_sg, xx, ss, mu_k, sg_k);
    linear_mfma_kernel<<<ggrid, 512, 0, stream>>>(mu_in, sg_in, wv_mu, wv_sg, xx, ss, mu_v, sg_v);

    attn_mfma_kernel<<<Bsz * H * (S / 64), 512, 0, stream>>>(mu_q, sg_q, mu_k, sg_k,
                                                             mu_v, sg_v, mu_a, sg_a);

    rowstats_kernel<<<NROWS / 4, 256, 0, stream>>>(mu_a, sg_a, xx2, ss2);
    linear_mfma_kernel<<<ggrid, 512, 0, stream>>>(mu_a, sg_a, wo_mu, wo_sg, xx2, ss2, out_mu, out_sg);
}

// Round 9
// 513.964 us; speedup vs baseline: 8.3548x; 1.0513x over previous
//
#include <hip/hip_runtime.h>
#include <math.h>

// VDP ViT attention block. R8: all-bf16 dataflow — linears write packed bf16,
// weights pre-transposed to bf16, attention staging is pure copies.
constexpr int E = 768;
constexpr int H = 12;
constexpr int D = 64;
constexpr int Bsz = 8;
constexpr int S = 512;
constexpr int NROWS = Bsz * S;            // 4096
constexpr int NE_ = NROWS * E;            // 3145728
constexpr int WE = E * E;                 // 589824
constexpr float LOG_PV_M1 = -5.605170185988091f;  // ln(0.01) - 1
constexpr float INV_PV = 100.0f;

typedef __attribute__((ext_vector_type(8))) short short8;
typedef __attribute__((ext_vector_type(4))) float floatx4;

__device__ __forceinline__ float softplusf(float x) {
    return fmaxf(x, 0.f) + log1pf(expf(-fabsf(x)));
}
__device__ __forceinline__ unsigned short f2bf(float f) {
    unsigned int u = __float_as_uint(f);
    unsigned int r = (u + 0x7fffu + ((u >> 16) & 1u)) >> 16;
    return (unsigned short)r;
}
__device__ __forceinline__ float bf2f(unsigned short h) {
    return __uint_as_float(((unsigned int)h) << 16);
}
__device__ __forceinline__ unsigned int pack2(float a, float b) {
    return (unsigned int)f2bf(a) | ((unsigned int)f2bf(b) << 16);
}

// ---------------- KL ----------------
__global__ void zero_kernel(float* p) { if (threadIdx.x == 0) p[0] = 0.f; }

__global__ __launch_bounds__(256) void kl_kernel(const float* __restrict__ wmu,
                                                 const float* __restrict__ wsig,
                                                 float* __restrict__ out) {
    int tid = blockIdx.x * 256 + threadIdx.x;
    int nthr = gridDim.x * 256;
    float partial = 0.f;
    for (int i = tid; i < E * E; i += nthr) {
        float w = wmu[i];
        partial += w * w;
    }
    partial *= INV_PV;
    if (tid < E) {
        float ws = wsig[tid];
        partial += (float)E * (LOG_PV_M1 - ws + softplusf(ws) * INV_PV);
    }
    __shared__ float red[256];
    red[threadIdx.x] = partial;
    __syncthreads();
    for (int s = 128; s > 0; s >>= 1) {
        if (threadIdx.x < s) red[threadIdx.x] += red[threadIdx.x + s];
        __syncthreads();
    }
    if (threadIdx.x == 0)
        atomicAdd(out, 0.5f * red[0] / (float)(E * E));
}

// ---------------- pre-pack kernels ----------------
__global__ __launch_bounds__(256) void pack_in_kernel(const float* __restrict__ mu,
                                                      const float* __restrict__ sg,
                                                      unsigned short* __restrict__ m16,
                                                      unsigned short* __restrict__ s16) {
    size_t i = ((size_t)blockIdx.x * 256 + threadIdx.x) * 8;
    float4 a0 = *(const float4*)(mu + i);
    float4 a1 = *(const float4*)(mu + i + 4);
    *(uint4*)(m16 + i) = make_uint4(pack2(a0.x, a0.y), pack2(a0.z, a0.w),
                                    pack2(a1.x, a1.y), pack2(a1.z, a1.w));
    float4 b0 = *(const float4*)(sg + i);
    float4 b1 = *(const float4*)(sg + i + 4);
    *(uint4*)(s16 + i) = make_uint4(pack2(b0.x, b0.y), pack2(b0.z, b0.w),
                                    pack2(b1.x, b1.y), pack2(b1.z, b1.w));
}

// transpose + bf16-pack weights: WT[n][k] = W[k][n]; WT_sg[n][k] = W[k][n]^2/768
__global__ __launch_bounds__(256) void packT_kernel(
    const float* __restrict__ w0, const float* __restrict__ w1,
    const float* __restrict__ w2, const float* __restrict__ w3,
    unsigned short* __restrict__ wtm, unsigned short* __restrict__ wts) {
    const float* W = (blockIdx.z == 0) ? w0 : (blockIdx.z == 1) ? w1
                   : (blockIdx.z == 2) ? w2 : w3;
    unsigned short* om = wtm + (size_t)blockIdx.z * WE;
    unsigned short* os = wts + (size_t)blockIdx.z * WE;
    __shared__ float tile[32][33];
    int k0 = blockIdx.x * 32, n0 = blockIdx.y * 32;
    int t = threadIdx.x;
    {
        int r = t >> 3, c = (t & 7) * 4;
        float4 v = *(const float4*)&W[(size_t)(k0 + r) * E + n0 + c];
        tile[r][c] = v.x; tile[r][c + 1] = v.y; tile[r][c + 2] = v.z; tile[r][c + 3] = v.w;
    }
    __syncthreads();
    {
        int n = t >> 3, r = (t & 7) * 4;
        float v0 = tile[r][n], v1 = tile[r + 1][n], v2 = tile[r + 2][n], v3 = tile[r + 3][n];
        size_t o = (size_t)(n0 + n) * E + k0 + r;
        *(uint2*)&om[o] = make_uint2(pack2(v0, v1), pack2(v2, v3));
        const float is = 1.f / 768.f;
        *(uint2*)&os[o] = make_uint2(pack2(v0 * v0 * is, v1 * v1 * is),
                                     pack2(v2 * v2 * is, v3 * v3 * is));
    }
}

// ---------------- row stats (fp32 inputs) ----------------
__global__ __launch_bounds__(256) void rowstats_kernel(const float* __restrict__ mu,
                                                       const float* __restrict__ sg,
                                                       float* __restrict__ xx,
                                                       float* __restrict__ ss) {
    int wave = threadIdx.x >> 6, lane = threadIdx.x & 63;
    int row = blockIdx.x * 4 + wave;
    const float* mrow = mu + (size_t)row * E;
    const float* srow = sg + (size_t)row * E;
    float s2 = 0.f, s1 = 0.f;
    for (int i = lane; i < E; i += 64) {
        float m = mrow[i];
        s2 += m * m;
        s1 += srow[i];
    }
    for (int off = 32; off > 0; off >>= 1) {
        s2 += __shfl_xor(s2, off);
        s1 += __shfl_xor(s1, off);
    }
    if (lane == 0) {
        xx[row] = s2 * (1.f / ((float)E * (float)E));
        ss[row] = s1;
    }
}

// ---------------- row stats (bf16 inputs) ----------------
__global__ __launch_bounds__(256) void rowstats16_kernel(const unsigned short* __restrict__ m16,
                                                         const unsigned short* __restrict__ s16,
                                                         float* __restrict__ xx,
                                                         float* __restrict__ ss) {
    int wave = threadIdx.x >> 6, lane = threadIdx.x & 63;
    int row = blockIdx.x * 4 + wave;
    const unsigned short* mrow = m16 + (size_t)row * E;
    const unsigned short* srow = s16 + (size_t)row * E;
    float s2 = 0.f, s1 = 0.f;
    for (int c = lane; c < 96; c += 64) {
        uint4 um = *(const uint4*)(mrow + c * 8);
        uint4 us = *(const uint4*)(srow + c * 8);
        unsigned int mw[4] = {um.x, um.y, um.z, um.w};
        unsigned int sw[4] = {us.x, us.y, us.z, us.w};
#pragma unroll
        for (int j = 0; j < 4; ++j) {
            float a = bf2f((unsigned short)(mw[j] & 0xffff));
            float b = bf2f((unsigned short)(mw[j] >> 16));
            s2 += a * a + b * b;
            s1 += bf2f((unsigned short)(sw[j] & 0xffff)) + bf2f((unsigned short)(sw[j] >> 16));
        }
    }
    for (int off = 32; off > 0; off >>= 1) {
        s2 += __shfl_xor(s2, off);
        s1 += __shfl_xor(s1, off);
    }
    if (lane == 0) {
        xx[row] = s2 * (1.f / ((float)E * (float)E));
        ss[row] = s1;
    }
}

// ---------------- MFMA dual-GEMM linear, bf16 in, role-typed out ----------------
// ROLE 0: out = (hi, lo, sg) bf16   [Q and K]
// ROLE 1: out = (mu, sg, mu^2+sg) bf16  [V]
// ROLE 2: out = (Cmu, Csg) fp32  [final]
template <int ROLE>
__global__ __launch_bounds__(512, 1) void linear2_kernel(
    const unsigned short* __restrict__ A16m, const unsigned short* __restrict__ A16s,
    const unsigned short* __restrict__ WTm, const unsigned short* __restrict__ WTs,
    const float* __restrict__ wsig, const float* __restrict__ xx, const float* __restrict__ ss,
    void* __restrict__ o0v, void* __restrict__ o1v, void* __restrict__ o2v) {
    constexpr int LDK = 40;
    __shared__ unsigned short A_mu[64][LDK], A_sg[64][LDK];
    __shared__ unsigned short W_mu[128][LDK], W_sg[128][LDK];
    const int m0 = blockIdx.x * 64, n0 = blockIdx.y * 128;
    const int t = threadIdx.x, lane = t & 63, wid = t >> 6;
    const int qsub = wid >> 1, c2 = wid & 1;
    const int lr = lane & 15, lg = lane >> 4;

    floatx4 accm[4] = {{0.f,0.f,0.f,0.f},{0.f,0.f,0.f,0.f},{0.f,0.f,0.f,0.f},{0.f,0.f,0.f,0.f}};
    floatx4 accs[4] = {{0.f,0.f,0.f,0.f},{0.f,0.f,0.f,0.f},{0.f,0.f,0.f,0.f},{0.f,0.f,0.f,0.f}};

    for (int k0 = 0; k0 < E; k0 += 32) {
        __syncthreads();
        {
            int r = t >> 3, c = (t & 7) * 4;
            *(uint2*)&A_mu[r][c] = *(const uint2*)(A16m + (size_t)(m0 + r) * E + k0 + c);
            *(uint2*)&A_sg[r][c] = *(const uint2*)(A16s + (size_t)(m0 + r) * E + k0 + c);
        }
        {
            int n = t >> 2, c = (t & 3) * 8;
            *(uint4*)&W_mu[n][c] = *(const uint4*)(WTm + (size_t)(n0 + n) * E + k0 + c);
            *(uint4*)&W_sg[n][c] = *(const uint4*)(WTs + (size_t)(n0 + n) * E + k0 + c);
        }
        __syncthreads();
        short8 a_mu = *(const short8*)&A_mu[qsub * 16 + lr][lg * 8];
        short8 a_sg = *(const short8*)&A_sg[qsub * 16 + lr][lg * 8];
#pragma unroll
        for (int f = 0; f < 4; ++f) {
            int col = c2 * 64 + f * 16 + lr;
            short8 b_mu = *(const short8*)&W_mu[col][lg * 8];
            short8 b_sg = *(const short8*)&W_sg[col][lg * 8];
            accm[f] = __builtin_amdgcn_mfma_f32_16x16x32_bf16(a_mu, b_mu, accm[f], 0, 0, 0);
            accs[f] = __builtin_amdgcn_mfma_f32_16x16x32_bf16(a_sg, b_sg, accs[f], 0, 0, 0);
        }
    }
#pragma unroll
    for (int f = 0; f < 4; ++f) {
        int n = n0 + c2 * 64 + f * 16 + lr;
        float WS = softplusf(wsig[n]);
#pragma unroll
        for (int v = 0; v < 4; ++v) {
            int m = m0 + qsub * 16 + lg * 4 + v;
            size_t off = (size_t)m * E + n;
            float mu = accm[f][v];
            float sgo = softplusf(accs[f][v] + xx[m] * WS + ss[m] * WS * (1.f / 768.f));
            if (ROLE == 0) {
                unsigned short hi = f2bf(mu);
                ((unsigned short*)o0v)[off] = hi;
                ((unsigned short*)o1v)[off] = f2bf(mu - bf2f(hi));
                ((unsigned short*)o2v)[off] = f2bf(sgo);
            } else if (ROLE == 1) {
                ((unsigned short*)o0v)[off] = f2bf(mu);
                ((unsigned short*)o1v)[off] = f2bf(sgo);
                ((unsigned short*)o2v)[off] = f2bf(mu * mu + sgo);
            } else {
                ((float*)o0v)[off] = mu;
                ((float*)o1v)[off] = sgo;
            }
        }
    }
}

// ---------------- MFMA attention, pure-copy staging ----------------
__global__ __launch_bounds__(512, 1) void attn2_kernel(
    const unsigned short* __restrict__ q_hi_g, const unsigned short* __restrict__ q_lo_g,
    const unsigned short* __restrict__ q_sg_g,
    const unsigned short* __restrict__ k_hi_g, const unsigned short* __restrict__ k_lo_g,
    const unsigned short* __restrict__ k_sg_g,
    const unsigned short* __restrict__ v_mu_g, const unsigned short* __restrict__ v_sg_g,
    const unsigned short* __restrict__ v_cb_g,
    unsigned short* __restrict__ a_m16, unsigned short* __restrict__ a_s16) {
    constexpr int QB = 64, KC = 64, LDK = 72;
    __shared__ unsigned short q_hi[QB][LDK], q_lo[QB][LDK], q_cb[QB][LDK], q_k2[QB][LDK];
    __shared__ unsigned short k_hi[KC][LDK], k_lo[KC][LDK], k_sg[KC][LDK], k_qsg[KC][LDK];
    __shared__ unsigned short vT_mu[D][LDK], vT_sg[D][LDK], vT_cb[D][LDK];
    __shared__ unsigned short p_w[QB][LDK], p_w2[QB][LDK], p_sw[QB][LDK];
    __shared__ float red_m[2][QB], red_z[2][QB];

    const int bid = blockIdx.x;
    const int qt = bid & 7;
    const int hb = bid >> 3;
    const int h = hb % H;
    const int b = hb / H;
    const int q0 = qt * QB;
    const int t = threadIdx.x;
    const int lane = t & 63, wid = t >> 6;
    const int qsub = wid >> 1, c2 = wid & 1;
    const int Q0 = qsub * 16;
    const int lr = lane & 15, lg = lane >> 4;
    const size_t base = (size_t)b * S * E + (size_t)h * D;

    // ---- q-side stage (once): copies + on-the-fly cb/k2 ----
    {
        int r = t >> 3, g = (t & 7) * 8;
        size_t off = base + (size_t)(q0 + r) * E + g;
        uint4 hi4 = *(const uint4*)(q_hi_g + off);
        uint4 lo4 = *(const uint4*)(q_lo_g + off);
        uint4 sg4 = *(const uint4*)(q_sg_g + off);
        uint4 kh4 = *(const uint4*)(k_hi_g + off);
        uint4 kl4 = *(const uint4*)(k_lo_g + off);
        *(uint4*)&q_hi[r][g] = hi4;
        *(uint4*)&q_lo[r][g] = lo4;
        unsigned int hw[4] = {hi4.x, hi4.y, hi4.z, hi4.w};
        unsigned int lw[4] = {lo4.x, lo4.y, lo4.z, lo4.w};
        unsigned int sw[4] = {sg4.x, sg4.y, sg4.z, sg4.w};
        unsigned int khw[4] = {kh4.x, kh4.y, kh4.z, kh4.w};
        unsigned int klw[4] = {kl4.x, kl4.y, kl4.z, kl4.w};
        unsigned int cbw[4], k2w[4];
        const float i64 = 1.f / 64.f;
#pragma unroll
        for (int j = 0; j < 4; ++j) {
            float m0f = bf2f((unsigned short)(hw[j] & 0xffff)) + bf2f((unsigned short)(lw[j] & 0xffff));
            float m1f = bf2f((unsigned short)(hw[j] >> 16)) + bf2f((unsigned short)(lw[j] >> 16));
            float s0f = bf2f((unsigned short)(sw[j] & 0xffff));
            float s1f = bf2f((unsigned short)(sw[j] >> 16));
            cbw[j] = pack2((m0f * m0f + s0f) * i64, (m1f * m1f + s1f) * i64);
            float km0 = bf2f((unsigned short)(khw[j] & 0xffff)) + bf2f((unsigned short)(klw[j] & 0xffff));
            float km1 = bf2f((unsigned short)(khw[j] >> 16)) + bf2f((unsigned short)(klw[j] >> 16));
            k2w[j] = pack2(km0 * km0 * i64, km1 * km1 * i64);
        }
        *(uint4*)&q_cb[r][g] = make_uint4(cbw[0], cbw[1], cbw[2], cbw[3]);
        *(uint4*)&q_k2[r][g] = make_uint4(k2w[0], k2w[1], k2w[2], k2w[3]);
    }

    // ---- pass 1: softmax stats ----
    float mv[4], zv[4];
#pragma unroll
    for (int v = 0; v < 4; ++v) { mv[v] = -1e30f; zv[v] = 0.f; }

    for (int c = 0; c < S / KC; ++c) {
        __syncthreads();
        {
            int r = t >> 3, g = (t & 7) * 8;
            size_t off = base + (size_t)(c * KC + r) * E + g;
            *(uint4*)&k_hi[r][g] = *(const uint4*)(k_hi_g + off);
            *(uint4*)&k_lo[r][g] = *(const uint4*)(k_lo_g + off);
        }
        __syncthreads();
        floatx4 cm[2] = {{0.f, 0.f, 0.f, 0.f}, {0.f, 0.f, 0.f, 0.f}};
#pragma unroll
        for (int ks = 0; ks < 2; ++ks) {
            int ao = lg * 8 + ks * 32;
            short8 ahi = *(const short8*)&q_hi[Q0 + lr][ao];
            short8 alo = *(const short8*)&q_lo[Q0 + lr][ao];
#pragma unroll
            for (int f = 0; f < 2; ++f) {
                int key = c2 * 32 + f * 16 + lr;
                short8 bhi = *(const short8*)&k_hi[key][ao];
                short8 blo = *(const short8*)&k_lo[key][ao];
                cm[f] = __builtin_amdgcn_mfma_f32_16x16x32_bf16(ahi, bhi, cm[f], 0, 0, 0);
                cm[f] = __builtin_amdgcn_mfma_f32_16x16x32_bf16(ahi, blo, cm[f], 0, 0, 0);
                cm[f] = __builtin_amdgcn_mfma_f32_16x16x32_bf16(alo, bhi, cm[f], 0, 0, 0);
            }
        }
#pragma unroll
        for (int v = 0; v < 4; ++v) {
            float s0 = cm[0][v] * 0.125f, s1 = cm[1][v] * 0.125f;
            float cmx = fmaxf(s0, s1);
            for (int off = 1; off <= 8; off <<= 1) cmx = fmaxf(cmx, __shfl_xor(cmx, off));
            float ez = __expf(s0 - cmx) + __expf(s1 - cmx);
            for (int off = 1; off <= 8; off <<= 1) ez += __shfl_xor(ez, off);
            float nm = fmaxf(mv[v], cmx);
            zv[v] = zv[v] * __expf(mv[v] - nm) + ez * __expf(cmx - nm);
            mv[v] = nm;
        }
    }
    __syncthreads();
    if ((lane & 15) == 0) {
#pragma unroll
        for (int v = 0; v < 4; ++v) {
            int qr = Q0 + lg * 4 + v;
            red_m[c2][qr] = mv[v];
            red_z[c2][qr] = zv[v];
        }
    }
    __syncthreads();
    float fm[4], fzi[4];
#pragma unroll
    for (int v = 0; v < 4; ++v) {
        int qr = Q0 + lg * 4 + v;
        float m0 = red_m[0][qr], m1 = red_m[1][qr];
        float mm = fmaxf(m0, m1);
        float zz = red_z[0][qr] * __expf(m0 - mm) + red_z[1][qr] * __expf(m1 - mm);
        fm[v] = mm;
        fzi[v] = 1.f / zz;
    }

    // ---- pass 2 ----
    floatx4 accm[2] = {{0.f, 0.f, 0.f, 0.f}, {0.f, 0.f, 0.f, 0.f}};
    floatx4 accs[2] = {{0.f, 0.f, 0.f, 0.f}, {0.f, 0.f, 0.f, 0.f}};
    for (int c = 0; c < S / KC; ++c) {
        __syncthreads();
        {   // K-side copies
            int r = t >> 3, g = (t & 7) * 8;
            size_t off = base + (size_t)(c * KC + r) * E + g;
            *(uint4*)&k_hi[r][g] = *(const uint4*)(k_hi_g + off);
            *(uint4*)&k_lo[r][g] = *(const uint4*)(k_lo_g + off);
            *(uint4*)&k_sg[r][g] = *(const uint4*)(k_sg_g + off);
            *(uint4*)&k_qsg[r][g] = *(const uint4*)(q_sg_g + off);
        }
        {   // V transpose: 2 keys x 4 d per thread, bit-interleave
            int kp = t & 31, dg = (t >> 5) * 4;
            size_t o0 = base + (size_t)(c * KC + 2 * kp) * E + dg;
            size_t o1 = o0 + E;
            uint2 am = *(const uint2*)(v_mu_g + o0), bm = *(const uint2*)(v_mu_g + o1);
            uint2 as_ = *(const uint2*)(v_sg_g + o0), bs_ = *(const uint2*)(v_sg_g + o1);
            uint2 ac = *(const uint2*)(v_cb_g + o0), bc = *(const uint2*)(v_cb_g + o1);
            *(unsigned int*)&vT_mu[dg + 0][2 * kp] = (am.x & 0xffffu) | (bm.x << 16);
            *(unsigned int*)&vT_mu[dg + 1][2 * kp] = (am.x >> 16) | (bm.x & 0xffff0000u);
            *(unsigned int*)&vT_mu[dg + 2][2 * kp] = (am.y & 0xffffu) | (bm.y << 16);
            *(unsigned int*)&vT_mu[dg + 3][2 * kp] = (am.y >> 16) | (bm.y & 0xffff0000u);
            *(unsigned int*)&vT_sg[dg + 0][2 * kp] = (as_.x & 0xffffu) | (bs_.x << 16);
            *(unsigned int*)&vT_sg[dg + 1][2 * kp] = (as_.x >> 16) | (bs_.x & 0xffff0000u);
            *(unsigned int*)&vT_sg[dg + 2][2 * kp] = (as_.y & 0xffffu) | (bs_.y << 16);
            *(unsigned int*)&vT_sg[dg + 3][2 * kp] = (as_.y >> 16) | (bs_.y & 0xffff0000u);
            *(unsigned int*)&vT_cb[dg + 0][2 * kp] = (ac.x & 0xffffu) | (bc.x << 16);
            *(unsigned int*)&vT_cb[dg + 1][2 * kp] = (ac.x >> 16) | (bc.x & 0xffff0000u);
            *(unsigned int*)&vT_cb[dg + 2][2 * kp] = (ac.y & 0xffffu) | (bc.y << 16);
            *(unsigned int*)&vT_cb[dg + 3][2 * kp] = (ac.y >> 16) | (bc.y & 0xffff0000u);
        }
        __syncthreads();
        // scores
        floatx4 cm[2] = {{0.f, 0.f, 0.f, 0.f}, {0.f, 0.f, 0.f, 0.f}};
        floatx4 cs[2] = {{0.f, 0.f, 0.f, 0.f}, {0.f, 0.f, 0.f, 0.f}};
#pragma unroll
        for (int ks = 0; ks < 2; ++ks) {
            int ao = lg * 8 + ks * 32;
            short8 ahi = *(const short8*)&q_hi[Q0 + lr][ao];
            short8 alo = *(const short8*)&q_lo[Q0 + lr][ao];
            short8 acb = *(const short8*)&q_cb[Q0 + lr][ao];
            short8 ak2 = *(const short8*)&q_k2[Q0 + lr][ao];
#pragma unroll
            for (int f = 0; f < 2; ++f) {
                int key = c2 * 32 + f * 16 + lr;
                short8 bhi = *(const short8*)&k_hi[key][ao];
                short8 blo = *(const short8*)&k_lo[key][ao];
                short8 bsg = *(const short8*)&k_sg[key][ao];
                short8 bqs = *(const short8*)&k_qsg[key][ao];
                cm[f] = __builtin_amdgcn_mfma_f32_16x16x32_bf16(ahi, bhi, cm[f], 0, 0, 0);
                cm[f] = __builtin_amdgcn_mfma_f32_16x16x32_bf16(ahi, blo, cm[f], 0, 0, 0);
                cm[f] = __builtin_amdgcn_mfma_f32_16x16x32_bf16(alo, bhi, cm[f], 0, 0, 0);
                cs[f] = __builtin_amdgcn_mfma_f32_16x16x32_bf16(acb, bsg, cs[f], 0, 0, 0);
                cs[f] = __builtin_amdgcn_mfma_f32_16x16x32_bf16(ak2, bqs, cs[f], 0, 0, 0);
            }
        }
        // w / Sigma_w -> P (p_w2 = w^2/512; p_sw = Sigma_w/512 => e,f get 1/512^2 total)
#pragma unroll
        for (int f = 0; f < 2; ++f)
#pragma unroll
            for (int v = 0; v < 4; ++v) {
                int qr = Q0 + lg * 4 + v;
                int key = c2 * 32 + f * 16 + lr;
                float w = __expf(cm[f][v] * 0.125f - fm[v]) * fzi[v];
                float sgs = cs[f][v] * (1.f / 64.f);
                float g1 = w - w * w;
                p_w[qr][key] = f2bf(w);
                p_w2[qr][key] = f2bf(w * w * (1.f / 512.f));
                p_sw[qr][key] = f2bf(g1 * g1 * sgs * (1.f / 262144.f));
            }
        __syncthreads();
        // PV
#pragma unroll
        for (int ks = 0; ks < 2; ++ks) {
            int ko = lg * 8 + ks * 32;
            short8 aw = *(const short8*)&p_w[Q0 + lr][ko];
            short8 aw2 = *(const short8*)&p_w2[Q0 + lr][ko];
            short8 asw = *(const short8*)&p_sw[Q0 + lr][ko];
#pragma unroll
            for (int nf = 0; nf < 2; ++nf) {
                int dcol = (wid & 1) * 32 + nf * 16 + lr;
                short8 bvm = *(const short8*)&vT_mu[dcol][ko];
                short8 bvs = *(const short8*)&vT_sg[dcol][ko];
                short8 bvc = *(const short8*)&vT_cb[dcol][ko];
                accm[nf] = __builtin_amdgcn_mfma_f32_16x16x32_bf16(aw, bvm, accm[nf], 0, 0, 0);
                accs[nf] = __builtin_amdgcn_mfma_f32_16x16x32_bf16(aw2, bvs, accs[nf], 0, 0, 0);
                accs[nf] = __builtin_amdgcn_mfma_f32_16x16x32_bf16(asw, bvc, accs[nf], 0, 0, 0);
            }
        }
    }
    // epilogue -> bf16
#pragma unroll
    for (int nf = 0; nf < 2; ++nf)
#pragma unroll
        for (int v = 0; v < 4; ++v) {
            int qg = q0 + Q0 + lg * 4 + v;
            int dcol = (wid & 1) * 32 + nf * 16 + lr;
            size_t g = base + (size_t)qg * E + dcol;
            a_m16[g] = f2bf(accm[nf][v]);
            a_s16[g] = f2bf(softplusf(accs[nf][v]));
        }
}

// ---------------- launch ----------------
extern "C" void kernel_launch(void* const* d_in, const int* in_sizes, int n_in,
                              void* d_out, int out_size, void* d_ws, size_t ws_size,
                              hipStream_t stream) {
    const float* mu_in = (const float*)d_in[0];
    const float* sg_in = (const float*)d_in[1];
    const float* wq_mu = (const float*)d_in[2];
    const float* wq_sg = (const float*)d_in[3];
    const float* wk_mu = (const float*)d_in[4];
    const float* wk_sg = (const float*)d_in[5];
    const float* wv_mu = (const float*)d_in[6];
    const float* wv_sg = (const float*)d_in[7];
    const float* wo_mu = (const float*)d_in[8];
    const float* wo_sg = (const float*)d_in[9];

    float* out_mu = (float*)d_out;
    float* out_sg = out_mu + (size_t)NE_;
    float* out_kl = out_sg + (size_t)NE_;

    unsigned short* sp = (unsigned short*)d_ws;
    unsigned short* in_m16 = sp;
    unsigned short* in_s16 = sp + (size_t)NE_;
    unsigned short* q_hi = sp + 2 * (size_t)NE_;
    unsigned short* q_lo = sp + 3 * (size_t)NE_;
    unsigned short* q_sg = sp + 4 * (size_t)NE_;
    unsigned short* k_hi = sp + 5 * (size_t)NE_;
    unsigned short* k_lo = sp + 6 * (size_t)NE_;
    unsigned short* k_sg = sp + 7 * (size_t)NE_;
    unsigned short* v_mu = sp + 8 * (size_t)NE_;
    unsigned short* v_sg = sp + 9 * (size_t)NE_;
    unsigned short* v_cb = sp + 10 * (size_t)NE_;
    unsigned short* a_m16 = sp + 11 * (size_t)NE_;
    unsigned short* a_s16 = sp + 12 * (size_t)NE_;
    unsigned short* wt_mu = sp + 13 * (size_t)NE_;
    unsigned short* wt_sg = wt_mu + 4 * (size_t)WE;
    float* fstats = (float*)(wt_sg + 4 * (size_t)WE);
    float* xx = fstats;
    float* ss = fstats + NROWS;
    float* xx2 = fstats + 2 * NROWS;
    float* ss2 = fstats + 3 * NROWS;

    zero_kernel<<<1, 64, 0, stream>>>(out_kl);
    kl_kernel<<<64, 256, 0, stream>>>(wq_mu, wq_sg, out_kl);
    kl_kernel<<<64, 256, 0, stream>>>(wk_mu, wk_sg, out_kl);
    kl_kernel<<<64, 256, 0, stream>>>(wv_mu, wv_sg, out_kl);
    kl_kernel<<<64, 256, 0, stream>>>(wo_mu, wo_sg, out_kl);

    pack_in_kernel<<<NE_ / 2048, 256, 0, stream>>>(mu_in, sg_in, in_m16, in_s16);
    packT_kernel<<<dim3(24, 24, 4), 256, 0, stream>>>(wq_mu, wk_mu, wv_mu, wo_mu, wt_mu, wt_sg);
    rowstats_kernel<<<NROWS / 4, 256, 0, stream>>>(mu_in, sg_in, xx, ss);

    dim3 ggrid(NROWS / 64, E / 128);
    linear2_kernel<0><<<ggrid, 512, 0, stream>>>(in_m16, in_s16, wt_mu, wt_sg,
                                                 wq_sg, xx, ss, q_hi, q_lo, q_sg);
    linear2_kernel<0><<<ggrid, 512, 0, stream>>>(in_m16, in_s16, wt_mu + (size_t)WE, wt_sg + (size_t)WE,
                                                 wk_sg, xx, ss, k_hi, k_lo, k_sg);
    linear2_kernel<1><<<ggrid, 512, 0, stream>>>(in_m16, in_s16, wt_mu + 2 * (size_t)WE, wt_sg + 2 * (size_t)WE,
                                                 wv_sg, xx, ss, v_mu, v_sg, v_cb);

    attn2_kernel<<<Bsz * H * (S / 64), 512, 0, stream>>>(q_hi, q_lo, q_sg, k_hi, k_lo, k_sg,
                                                         v_mu, v_sg, v_cb, a_m16, a_s16);

    rowstats16_kernel<<<NROWS / 4, 256, 0, stream>>>(a_m16, a_s16, xx2, ss2);
    linear2_kernel<2><<<ggrid, 512, 0, stream>>>(a_m16, a_s16, wt_mu + 3 * (size_t)WE, wt_sg + 3 * (size_t)WE,
                                                 wo_sg, xx2, ss2, out_mu, out_sg, nullptr);
}

// Round 12
// 495.000 us; speedup vs baseline: 8.6749x; 1.0383x over previous
//
#include <hip/hip_runtime.h>
#include <math.h>

// VDP ViT attention block. R9: occupancy attack — QB=32 union-LDS attention
// (2 blocks/CU) + XCD swizzle + fused QKV linear dispatch.
constexpr int E = 768;
constexpr int H = 12;
constexpr int D = 64;
constexpr int Bsz = 8;
constexpr int S = 512;
constexpr int NROWS = Bsz * S;            // 4096
constexpr int NE_ = NROWS * E;            // 3145728
constexpr int WE = E * E;                 // 589824
constexpr float LOG_PV_M1 = -5.605170185988091f;  // ln(0.01) - 1
constexpr float INV_PV = 100.0f;

typedef __attribute__((ext_vector_type(8))) short short8;
typedef __attribute__((ext_vector_type(4))) float floatx4;

__device__ __forceinline__ float softplusf(float x) {
    return fmaxf(x, 0.f) + log1pf(expf(-fabsf(x)));
}
__device__ __forceinline__ unsigned short f2bf(float f) {
    unsigned int u = __float_as_uint(f);
    unsigned int r = (u + 0x7fffu + ((u >> 16) & 1u)) >> 16;
    return (unsigned short)r;
}
__device__ __forceinline__ float bf2f(unsigned short h) {
    return __uint_as_float(((unsigned int)h) << 16);
}
__device__ __forceinline__ unsigned int pack2(float a, float b) {
    return (unsigned int)f2bf(a) | ((unsigned int)f2bf(b) << 16);
}

// ---------------- KL ----------------
__global__ void zero_kernel(float* p) { if (threadIdx.x == 0) p[0] = 0.f; }

__global__ __launch_bounds__(256) void kl_kernel(const float* __restrict__ wmu,
                                                 const float* __restrict__ wsig,
                                                 float* __restrict__ out) {
    int tid = blockIdx.x * 256 + threadIdx.x;
    int nthr = gridDim.x * 256;
    float partial = 0.f;
    for (int i = tid; i < E * E; i += nthr) {
        float w = wmu[i];
        partial += w * w;
    }
    partial *= INV_PV;
    if (tid < E) {
        float ws = wsig[tid];
        partial += (float)E * (LOG_PV_M1 - ws + softplusf(ws) * INV_PV);
    }
    __shared__ float red[256];
    red[threadIdx.x] = partial;
    __syncthreads();
    for (int s = 128; s > 0; s >>= 1) {
        if (threadIdx.x < s) red[threadIdx.x] += red[threadIdx.x + s];
        __syncthreads();
    }
    if (threadIdx.x == 0)
        atomicAdd(out, 0.5f * red[0] / (float)(E * E));
}

// ---------------- pre-pack kernels ----------------
__global__ __launch_bounds__(256) void pack_in_kernel(const float* __restrict__ mu,
                                                      const float* __restrict__ sg,
                                                      unsigned short* __restrict__ m16,
                                                      unsigned short* __restrict__ s16) {
    size_t i = ((size_t)blockIdx.x * 256 + threadIdx.x) * 8;
    float4 a0 = *(const float4*)(mu + i);
    float4 a1 = *(const float4*)(mu + i + 4);
    *(uint4*)(m16 + i) = make_uint4(pack2(a0.x, a0.y), pack2(a0.z, a0.w),
                                    pack2(a1.x, a1.y), pack2(a1.z, a1.w));
    float4 b0 = *(const float4*)(sg + i);
    float4 b1 = *(const float4*)(sg + i + 4);
    *(uint4*)(s16 + i) = make_uint4(pack2(b0.x, b0.y), pack2(b0.z, b0.w),
                                    pack2(b1.x, b1.y), pack2(b1.z, b1.w));
}

__global__ __launch_bounds__(256) void packT_kernel(
    const float* __restrict__ w0, const float* __restrict__ w1,
    const float* __restrict__ w2, const float* __restrict__ w3,
    unsigned short* __restrict__ wtm, unsigned short* __restrict__ wts) {
    const float* W = (blockIdx.z == 0) ? w0 : (blockIdx.z == 1) ? w1
                   : (blockIdx.z == 2) ? w2 : w3;
    unsigned short* om = wtm + (size_t)blockIdx.z * WE;
    unsigned short* os = wts + (size_t)blockIdx.z * WE;
    __shared__ float tile[32][33];
    int k0 = blockIdx.x * 32, n0 = blockIdx.y * 32;
    int t = threadIdx.x;
    {
        int r = t >> 3, c = (t & 7) * 4;
        float4 v = *(const float4*)&W[(size_t)(k0 + r) * E + n0 + c];
        tile[r][c] = v.x; tile[r][c + 1] = v.y; tile[r][c + 2] = v.z; tile[r][c + 3] = v.w;
    }
    __syncthreads();
    {
        int n = t >> 3, r = (t & 7) * 4;
        float v0 = tile[r][n], v1 = tile[r + 1][n], v2 = tile[r + 2][n], v3 = tile[r + 3][n];
        size_t o = (size_t)(n0 + n) * E + k0 + r;
        *(uint2*)&om[o] = make_uint2(pack2(v0, v1), pack2(v2, v3));
        const float is = 1.f / 768.f;
        *(uint2*)&os[o] = make_uint2(pack2(v0 * v0 * is, v1 * v1 * is),
                                     pack2(v2 * v2 * is, v3 * v3 * is));
    }
}

// ---------------- row stats ----------------
__global__ __launch_bounds__(256) void rowstats_kernel(const float* __restrict__ mu,
                                                       const float* __restrict__ sg,
                                                       float* __restrict__ xx,
                                                       float* __restrict__ ss) {
    int wave = threadIdx.x >> 6, lane = threadIdx.x & 63;
    int row = blockIdx.x * 4 + wave;
    const float* mrow = mu + (size_t)row * E;
    const float* srow = sg + (size_t)row * E;
    float s2 = 0.f, s1 = 0.f;
    for (int i = lane; i < E; i += 64) {
        float m = mrow[i];
        s2 += m * m;
        s1 += srow[i];
    }
    for (int off = 32; off > 0; off >>= 1) {
        s2 += __shfl_xor(s2, off);
        s1 += __shfl_xor(s1, off);
    }
    if (lane == 0) {
        xx[row] = s2 * (1.f / ((float)E * (float)E));
        ss[row] = s1;
    }
}

__global__ __launch_bounds__(256) void rowstats16_kernel(const unsigned short* __restrict__ m16,
                                                         const unsigned short* __restrict__ s16,
                                                         float* __restrict__ xx,
                                                         float* __restrict__ ss) {
    int wave = threadIdx.x >> 6, lane = threadIdx.x & 63;
    int row = blockIdx.x * 4 + wave;
    const unsigned short* mrow = m16 + (size_t)row * E;
    const unsigned short* srow = s16 + (size_t)row * E;
    float s2 = 0.f, s1 = 0.f;
    for (int c = lane; c < 96; c += 64) {
        uint4 um = *(const uint4*)(mrow + c * 8);
        uint4 us = *(const uint4*)(srow + c * 8);
        unsigned int mw[4] = {um.x, um.y, um.z, um.w};
        unsigned int sw[4] = {us.x, us.y, us.z, us.w};
#pragma unroll
        for (int j = 0; j < 4; ++j) {
            float a = bf2f((unsigned short)(mw[j] & 0xffff));
            float b = bf2f((unsigned short)(mw[j] >> 16));
            s2 += a * a + b * b;
            s1 += bf2f((unsigned short)(sw[j] & 0xffff)) + bf2f((unsigned short)(sw[j] >> 16));
        }
    }
    for (int off = 32; off > 0; off >>= 1) {
        s2 += __shfl_xor(s2, off);
        s1 += __shfl_xor(s1, off);
    }
    if (lane == 0) {
        xx[row] = s2 * (1.f / ((float)E * (float)E));
        ss[row] = s1;
    }
}

// ---------------- fused QKV MFMA dual-GEMM (blockIdx.z = 0:Q 1:K 2:V) ----------------
__global__ __launch_bounds__(512, 1) void linear_qkv_kernel(
    const unsigned short* __restrict__ A16m, const unsigned short* __restrict__ A16s,
    const unsigned short* __restrict__ wt_mu, const unsigned short* __restrict__ wt_sg,
    const float* __restrict__ wq_sig, const float* __restrict__ wk_sig,
    const float* __restrict__ wv_sig,
    const float* __restrict__ xx, const float* __restrict__ ss,
    unsigned short* __restrict__ q_hi_g, unsigned short* __restrict__ q_lo_g,
    unsigned short* __restrict__ q_sg_g,
    unsigned short* __restrict__ k_hi_g, unsigned short* __restrict__ k_lo_g,
    unsigned short* __restrict__ k_sg_g,
    unsigned short* __restrict__ v_mu_g, unsigned short* __restrict__ v_sg_g,
    unsigned short* __restrict__ v_cb_g) {
    constexpr int LDK = 40;
    __shared__ unsigned short A_mu[64][LDK], A_sg[64][LDK];
    __shared__ unsigned short W_mu[128][LDK], W_sg[128][LDK];
    const int z = blockIdx.z;
    const unsigned short* WTm = wt_mu + (size_t)z * WE;
    const unsigned short* WTs = wt_sg + (size_t)z * WE;
    const float* wsig = (z == 0) ? wq_sig : (z == 1) ? wk_sig : wv_sig;
    const int m0 = blockIdx.x * 64, n0 = blockIdx.y * 128;
    const int t = threadIdx.x, lane = t & 63, wid = t >> 6;
    const int qsub = wid >> 1, c2 = wid & 1;
    const int lr = lane & 15, lg = lane >> 4;

    floatx4 accm[4] = {{0.f,0.f,0.f,0.f},{0.f,0.f,0.f,0.f},{0.f,0.f,0.f,0.f},{0.f,0.f,0.f,0.f}};
    floatx4 accs[4] = {{0.f,0.f,0.f,0.f},{0.f,0.f,0.f,0.f},{0.f,0.f,0.f,0.f},{0.f,0.f,0.f,0.f}};

    for (int k0 = 0; k0 < E; k0 += 32) {
        __syncthreads();
        {
            int r = t >> 3, c = (t & 7) * 4;
            *(uint2*)&A_mu[r][c] = *(const uint2*)(A16m + (size_t)(m0 + r) * E + k0 + c);
            *(uint2*)&A_sg[r][c] = *(const uint2*)(A16s + (size_t)(m0 + r) * E + k0 + c);
        }
        {
            int n = t >> 2, c = (t & 3) * 8;
            *(uint4*)&W_mu[n][c] = *(const uint4*)(WTm + (size_t)(n0 + n) * E + k0 + c);
            *(uint4*)&W_sg[n][c] = *(const uint4*)(WTs + (size_t)(n0 + n) * E + k0 + c);
        }
        __syncthreads();
        short8 a_mu = *(const short8*)&A_mu[qsub * 16 + lr][lg * 8];
        short8 a_sg = *(const short8*)&A_sg[qsub * 16 + lr][lg * 8];
#pragma unroll
        for (int f = 0; f < 4; ++f) {
            int col = c2 * 64 + f * 16 + lr;
            short8 b_mu = *(const short8*)&W_mu[col][lg * 8];
            short8 b_sg = *(const short8*)&W_sg[col][lg * 8];
            accm[f] = __builtin_amdgcn_mfma_f32_16x16x32_bf16(a_mu, b_mu, accm[f], 0, 0, 0);
            accs[f] = __builtin_amdgcn_mfma_f32_16x16x32_bf16(a_sg, b_sg, accs[f], 0, 0, 0);
        }
    }
#pragma unroll
    for (int f = 0; f < 4; ++f) {
        int n = n0 + c2 * 64 + f * 16 + lr;
        float WS = softplusf(wsig[n]);
#pragma unroll
        for (int v = 0; v < 4; ++v) {
            int m = m0 + qsub * 16 + lg * 4 + v;
            size_t off = (size_t)m * E + n;
            float mu = accm[f][v];
            float sgo = softplusf(accs[f][v] + xx[m] * WS + ss[m] * WS * (1.f / 768.f));
            if (z == 0) {
                unsigned short hi = f2bf(mu);
                q_hi_g[off] = hi;
                q_lo_g[off] = f2bf(mu - bf2f(hi));
                q_sg_g[off] = f2bf(sgo);
            } else if (z == 1) {
                unsigned short hi = f2bf(mu);
                k_hi_g[off] = hi;
                k_lo_g[off] = f2bf(mu - bf2f(hi));
                k_sg_g[off] = f2bf(sgo);
            } else {
                v_mu_g[off] = f2bf(mu);
                v_sg_g[off] = f2bf(sgo);
                v_cb_g[off] = f2bf(mu * mu + sgo);
            }
        }
    }
}

// ---------------- final linear (fp32 out) ----------------
__global__ __launch_bounds__(512, 1) void linear_out_kernel(
    const unsigned short* __restrict__ A16m, const unsigned short* __restrict__ A16s,
    const unsigned short* __restrict__ WTm, const unsigned short* __restrict__ WTs,
    const float* __restrict__ wsig, const float* __restrict__ xx, const float* __restrict__ ss,
    float* __restrict__ Cmu, float* __restrict__ Csg) {
    constexpr int LDK = 40;
    __shared__ unsigned short A_mu[64][LDK], A_sg[64][LDK];
    __shared__ unsigned short W_mu[128][LDK], W_sg[128][LDK];
    const int m0 = blockIdx.x * 64, n0 = blockIdx.y * 128;
    const int t = threadIdx.x, lane = t & 63, wid = t >> 6;
    const int qsub = wid >> 1, c2 = wid & 1;
    const int lr = lane & 15, lg = lane >> 4;

    floatx4 accm[4] = {{0.f,0.f,0.f,0.f},{0.f,0.f,0.f,0.f},{0.f,0.f,0.f,0.f},{0.f,0.f,0.f,0.f}};
    floatx4 accs[4] = {{0.f,0.f,0.f,0.f},{0.f,0.f,0.f,0.f},{0.f,0.f,0.f,0.f},{0.f,0.f,0.f,0.f}};

    for (int k0 = 0; k0 < E; k0 += 32) {
        __syncthreads();
        {
            int r = t >> 3, c = (t & 7) * 4;
            *(uint2*)&A_mu[r][c] = *(const uint2*)(A16m + (size_t)(m0 + r) * E + k0 + c);
            *(uint2*)&A_sg[r][c] = *(const uint2*)(A16s + (size_t)(m0 + r) * E + k0 + c);
        }
        {
            int n = t >> 2, c = (t & 3) * 8;
            *(uint4*)&W_mu[n][c] = *(const uint4*)(WTm + (size_t)(n0 + n) * E + k0 + c);
            *(uint4*)&W_sg[n][c] = *(const uint4*)(WTs + (size_t)(n0 + n) * E + k0 + c);
        }
        __syncthreads();
        short8 a_mu = *(const short8*)&A_mu[qsub * 16 + lr][lg * 8];
        short8 a_sg = *(const short8*)&A_sg[qsub * 16 + lr][lg * 8];
#pragma unroll
        for (int f = 0; f < 4; ++f) {
            int col = c2 * 64 + f * 16 + lr;
            short8 b_mu = *(const short8*)&W_mu[col][lg * 8];
            short8 b_sg = *(const short8*)&W_sg[col][lg * 8];
            accm[f] = __builtin_amdgcn_mfma_f32_16x16x32_bf16(a_mu, b_mu, accm[f], 0, 0, 0);
            accs[f] = __builtin_amdgcn_mfma_f32_16x16x32_bf16(a_sg, b_sg, accs[f], 0, 0, 0);
        }
    }
#pragma unroll
    for (int f = 0; f < 4; ++f) {
        int n = n0 + c2 * 64 + f * 16 + lr;
        float WS = softplusf(wsig[n]);
#pragma unroll
        for (int v = 0; v < 4; ++v) {
            int m = m0 + qsub * 16 + lg * 4 + v;
            size_t off = (size_t)m * E + n;
            Cmu[off] = accm[f][v];
            Csg[off] = softplusf(accs[f][v] + xx[m] * WS + ss[m] * WS * (1.f / 768.f));
        }
    }
}

// ---------------- MFMA attention: QB=32, union LDS (~70KB), 2 blocks/CU ----------------
// 8 waves: qsub=wid>>2 (16-row q-subtile), kq=wid&3 (16-key / 16-d quarter).
// uni[]: K-phase view {k_hi,k_lo,k_sg,k_qsg}; V-phase view {vT_mu,vT_sg,vT_cb}.
// Block swizzle: physical p -> logical L=(p&7)*192+(p>>3) so each XCD owns 12 heads.
__global__ __launch_bounds__(512, 2) void attn3_kernel(
    const unsigned short* __restrict__ q_hi_g, const unsigned short* __restrict__ q_lo_g,
    const unsigned short* __restrict__ q_sg_g,
    const unsigned short* __restrict__ k_hi_g, const unsigned short* __restrict__ k_lo_g,
    const unsigned short* __restrict__ k_sg_g,
    const unsigned short* __restrict__ v_mu_g, const unsigned short* __restrict__ v_sg_g,
    const unsigned short* __restrict__ v_cb_g,
    unsigned short* __restrict__ a_m16, unsigned short* __restrict__ a_s16) {
    constexpr int QB = 32, KC = 64, LDK = 72;
    __shared__ unsigned short q_hi[QB][LDK], q_lo[QB][LDK], q_cb[QB][LDK], q_k2[QB][LDK];
    __shared__ unsigned short p_w[QB][LDK], p_w2[QB][LDK], p_sw[QB][LDK];
    __shared__ unsigned short uni[4][KC][LDK];
    __shared__ float red_m[4][QB], red_z[4][QB];

    const int p = blockIdx.x;
    const int L = (p & 7) * 192 + (p >> 3);
    const int qt = L & 15;
    const int hb = L >> 4;
    const int h = hb % H;
    const int b = hb / H;
    const int q0 = qt * QB;
    const int t = threadIdx.x;
    const int lane = t & 63, wid = t >> 6;
    const int qsub = wid >> 2, kq = wid & 3;
    const int Q0 = qsub * 16;
    const int lr = lane & 15, lg = lane >> 4;
    const size_t base = (size_t)b * S * E + (size_t)h * D;

    // ---- q-side stage (once) ----
    {
        int r = t >> 4, g = (t & 15) * 4;
        size_t off = base + (size_t)(q0 + r) * E + g;
        uint2 hi2 = *(const uint2*)(q_hi_g + off);
        uint2 lo2 = *(const uint2*)(q_lo_g + off);
        uint2 sg2 = *(const uint2*)(q_sg_g + off);
        uint2 kh2 = *(const uint2*)(k_hi_g + off);
        uint2 kl2 = *(const uint2*)(k_lo_g + off);
        *(uint2*)&q_hi[r][g] = hi2;
        *(uint2*)&q_lo[r][g] = lo2;
        unsigned int hw[2] = {hi2.x, hi2.y}, lw[2] = {lo2.x, lo2.y};
        unsigned int sw[2] = {sg2.x, sg2.y};
        unsigned int khw[2] = {kh2.x, kh2.y}, klw[2] = {kl2.x, kl2.y};
        unsigned int cbw[2], k2w[2];
        const float i64 = 1.f / 64.f;
#pragma unroll
        for (int j = 0; j < 2; ++j) {
            float m0f = bf2f((unsigned short)(hw[j] & 0xffff)) + bf2f((unsigned short)(lw[j] & 0xffff));
            float m1f = bf2f((unsigned short)(hw[j] >> 16)) + bf2f((unsigned short)(lw[j] >> 16));
            float s0f = bf2f((unsigned short)(sw[j] & 0xffff));
            float s1f = bf2f((unsigned short)(sw[j] >> 16));
            cbw[j] = pack2((m0f * m0f + s0f) * i64, (m1f * m1f + s1f) * i64);
            float km0 = bf2f((unsigned short)(khw[j] & 0xffff)) + bf2f((unsigned short)(klw[j] & 0xffff));
            float km1 = bf2f((unsigned short)(khw[j] >> 16)) + bf2f((unsigned short)(klw[j] >> 16));
            k2w[j] = pack2(km0 * km0 * i64, km1 * km1 * i64);
        }
        *(uint2*)&q_cb[r][g] = make_uint2(cbw[0], cbw[1]);
        *(uint2*)&q_k2[r][g] = make_uint2(k2w[0], k2w[1]);
    }

    // ---- pass 1: softmax stats ----
    float mv[4], zv[4];
#pragma unroll
    for (int v = 0; v < 4; ++v) { mv[v] = -1e30f; zv[v] = 0.f; }

    for (int c = 0; c < S / KC; ++c) {
        __syncthreads();
        {
            int r = t >> 3, g = (t & 7) * 8;
            size_t off = base + (size_t)(c * KC + r) * E + g;
            *(uint4*)&uni[0][r][g] = *(const uint4*)(k_hi_g + off);
            *(uint4*)&uni[1][r][g] = *(const uint4*)(k_lo_g + off);
        }
        __syncthreads();
        floatx4 cm = {0.f, 0.f, 0.f, 0.f};
#pragma unroll
        for (int ks = 0; ks < 2; ++ks) {
            int ao = lg * 8 + ks * 32;
            short8 ahi = *(const short8*)&q_hi[Q0 + lr][ao];
            short8 alo = *(const short8*)&q_lo[Q0 + lr][ao];
            int key = kq * 16 + lr;
            short8 bhi = *(const short8*)&uni[0][key][ao];
            short8 blo = *(const short8*)&uni[1][key][ao];
            cm = __builtin_amdgcn_mfma_f32_16x16x32_bf16(ahi, bhi, cm, 0, 0, 0);
            cm = __builtin_amdgcn_mfma_f32_16x16x32_bf16(ahi, blo, cm, 0, 0, 0);
            cm = __builtin_amdgcn_mfma_f32_16x16x32_bf16(alo, bhi, cm, 0, 0, 0);
        }
#pragma unroll
        for (int v = 0; v < 4; ++v) {
            float s = cm[v] * 0.125f;
            float cmx = s;
            for (int off = 1; off <= 8; off <<= 1) cmx = fmaxf(cmx, __shfl_xor(cmx, off));
            float ez = __expf(s - cmx);
            for (int off = 1; off <= 8; off <<= 1) ez += __shfl_xor(ez, off);
            float nm = fmaxf(mv[v], cmx);
            zv[v] = zv[v] * __expf(mv[v] - nm) + ez * __expf(cmx - nm);
            mv[v] = nm;
        }
    }
    __syncthreads();
    if (lr == 0) {
#pragma unroll
        for (int v = 0; v < 4; ++v) {
            int qr = Q0 + lg * 4 + v;
            red_m[kq][qr] = mv[v];
            red_z[kq][qr] = zv[v];
        }
    }
    __syncthreads();
    float fm[4], fzi[4];
#pragma unroll
    for (int v = 0; v < 4; ++v) {
        int qr = Q0 + lg * 4 + v;
        float m01 = fmaxf(red_m[0][qr], red_m[1][qr]);
        float m23 = fmaxf(red_m[2][qr], red_m[3][qr]);
        float mm = fmaxf(m01, m23);
        float zz = red_z[0][qr] * __expf(red_m[0][qr] - mm)
                 + red_z[1][qr] * __expf(red_m[1][qr] - mm)
                 + red_z[2][qr] * __expf(red_m[2][qr] - mm)
                 + red_z[3][qr] * __expf(red_m[3][qr] - mm);
        fm[v] = mm;
        fzi[v] = 1.f / zz;
    }

    // ---- pass 2 ----
    floatx4 accm = {0.f, 0.f, 0.f, 0.f};
    floatx4 accs = {0.f, 0.f, 0.f, 0.f};
    for (int c = 0; c < S / KC; ++c) {
        __syncthreads();
        {   // K-phase staging into uni
            int r = t >> 3, g = (t & 7) * 8;
            size_t off = base + (size_t)(c * KC + r) * E + g;
            *(uint4*)&uni[0][r][g] = *(const uint4*)(k_hi_g + off);
            *(uint4*)&uni[1][r][g] = *(const uint4*)(k_lo_g + off);
            *(uint4*)&uni[2][r][g] = *(const uint4*)(k_sg_g + off);
            *(uint4*)&uni[3][r][g] = *(const uint4*)(q_sg_g + off);
        }
        __syncthreads();
        floatx4 cm = {0.f, 0.f, 0.f, 0.f};
        floatx4 cs = {0.f, 0.f, 0.f, 0.f};
#pragma unroll
        for (int ks = 0; ks < 2; ++ks) {
            int ao = lg * 8 + ks * 32;
            short8 ahi = *(const short8*)&q_hi[Q0 + lr][ao];
            short8 alo = *(const short8*)&q_lo[Q0 + lr][ao];
            short8 acb = *(const short8*)&q_cb[Q0 + lr][ao];
            short8 ak2 = *(const short8*)&q_k2[Q0 + lr][ao];
            int key = kq * 16 + lr;
            short8 bhi = *(const short8*)&uni[0][key][ao];
            short8 blo = *(const short8*)&uni[1][key][ao];
            short8 bsg = *(const short8*)&uni[2][key][ao];
            short8 bqs = *(const short8*)&uni[3][key][ao];
            cm = __builtin_amdgcn_mfma_f32_16x16x32_bf16(ahi, bhi, cm, 0, 0, 0);
            cm = __builtin_amdgcn_mfma_f32_16x16x32_bf16(ahi, blo, cm, 0, 0, 0);
            cm = __builtin_amdgcn_mfma_f32_16x16x32_bf16(alo, bhi, cm, 0, 0, 0);
            cs = __builtin_amdgcn_mfma_f32_16x16x32_bf16(acb, bsg, cs, 0, 0, 0);
            cs = __builtin_amdgcn_mfma_f32_16x16x32_bf16(ak2, bqs, cs, 0, 0, 0);
        }
        // w / Sigma_w -> P
#pragma unroll
        for (int v = 0; v < 4; ++v) {
            int qr = Q0 + lg * 4 + v;
            int key = kq * 16 + lr;
            float w = __expf(cm[v] * 0.125f - fm[v]) * fzi[v];
            float sgs = cs[v] * (1.f / 64.f);
            float g1 = w - w * w;
            p_w[qr][key] = f2bf(w);
            p_w2[qr][key] = f2bf(w * w * (1.f / 512.f));
            p_sw[qr][key] = f2bf(g1 * g1 * sgs * (1.f / 262144.f));  // 1/512^2
        }
        __syncthreads();
        {   // V-phase staging into uni (transposed)
            int kp = t & 31, dg = (t >> 5) * 4;
            size_t o0 = base + (size_t)(c * KC + 2 * kp) * E + dg;
            size_t o1 = o0 + E;
            uint2 am = *(const uint2*)(v_mu_g + o0), bm = *(const uint2*)(v_mu_g + o1);
            uint2 as_ = *(const uint2*)(v_sg_g + o0), bs_ = *(const uint2*)(v_sg_g + o1);
            uint2 ac = *(const uint2*)(v_cb_g + o0), bc = *(const uint2*)(v_cb_g + o1);
            *(unsigned int*)&uni[0][dg + 0][2 * kp] = (am.x & 0xffffu) | (bm.x << 16);
            *(unsigned int*)&uni[0][dg + 1][2 * kp] = (am.x >> 16) | (bm.x & 0xffff0000u);
            *(unsigned int*)&uni[0][dg + 2][2 * kp] = (am.y & 0xffffu) | (bm.y << 16);
            *(unsigned int*)&uni[0][dg + 3][2 * kp] = (am.y >> 16) | (bm.y & 0xffff0000u);
            *(unsigned int*)&uni[1][dg + 0][2 * kp] = (as_.x & 0xffffu) | (bs_.x << 16);
            *(unsigned int*)&uni[1][dg + 1][2 * kp] = (as_.x >> 16) | (bs_.x & 0xffff0000u);
            *(unsigned int*)&uni[1][dg + 2][2 * kp] = (as_.y & 0xffffu) | (bs_.y << 16);
            *(unsigned int*)&uni[1][dg + 3][2 * kp] = (as_.y >> 16) | (bs_.y & 0xffff0000u);
            *(unsigned int*)&uni[2][dg + 0][2 * kp] = (ac.x & 0xffffu) | (bc.x << 16);
            *(unsigned int*)&uni[2][dg + 1][2 * kp] = (ac.x >> 16) | (bc.x & 0xffff0000u);
            *(unsigned int*)&uni[2][dg + 2][2 * kp] = (ac.y & 0xffffu) | (bc.y << 16);
            *(unsigned int*)&uni[2][dg + 3][2 * kp] = (ac.y >> 16) | (bc.y & 0xffff0000u);
        }
        __syncthreads();
        // PV
#pragma unroll
        for (int ks = 0; ks < 2; ++ks) {
            int ko = lg * 8 + ks * 32;
            short8 aw = *(const short8*)&p_w[Q0 + lr][ko];
            short8 aw2 = *(const short8*)&p_w2[Q0 + lr][ko];
            short8 asw = *(const short8*)&p_sw[Q0 + lr][ko];
            int dcol = kq * 16 + lr;
            short8 bvm = *(const short8*)&uni[0][dcol][ko];
            short8 bvs = *(const short8*)&uni[1][dcol][ko];
            short8 bvc = *(const short8*)&uni[2][dcol][ko];
            accm = __builtin_amdgcn_mfma_f32_16x16x32_bf16(aw, bvm, accm, 0, 0, 0);
            accs = __builtin_amdgcn_mfma_f32_16x16x32_bf16(aw2, bvs, accs, 0, 0, 0);
            accs = __builtin_amdgcn_mfma_f32_16x16x32_bf16(asw, bvc, accs, 0, 0, 0);
        }
    }
    // epilogue -> bf16
#pragma unroll
    for (int v = 0; v < 4; ++v) {
        int qg = q0 + Q0 + lg * 4 + v;
        int dcol = kq * 16 + lr;
        size_t g = base + (size_t)qg * E + dcol;
        a_m16[g] = f2bf(accm[v]);
        a_s16[g] = f2bf(softplusf(accs[v]));
    }
}

// ---------------- launch ----------------
extern "C" void kernel_launch(void* const* d_in, const int* in_sizes, int n_in,
                              void* d_out, int out_size, void* d_ws, size_t ws_size,
                              hipStream_t stream) {
    const float* mu_in = (const float*)d_in[0];
    const float* sg_in = (const float*)d_in[1];
    const float* wq_mu = (const float*)d_in[2];
    const float* wq_sg = (const float*)d_in[3];
    const float* wk_mu = (const float*)d_in[4];
    const float* wk_sg = (const float*)d_in[5];
    const float* wv_mu = (const float*)d_in[6];
    const float* wv_sg = (const float*)d_in[7];
    const float* wo_mu = (const float*)d_in[8];
    const float* wo_sg = (const float*)d_in[9];

    float* out_mu = (float*)d_out;
    float* out_sg = out_mu + (size_t)NE_;
    float* out_kl = out_sg + (size_t)NE_;

    unsigned short* sp = (unsigned short*)d_ws;
    unsigned short* in_m16 = sp;
    unsigned short* in_s16 = sp + (size_t)NE_;
    unsigned short* q_hi = sp + 2 * (size_t)NE_;
    unsigned short* q_lo = sp + 3 * (size_t)NE_;
    unsigned short* q_sg = sp + 4 * (size_t)NE_;
    unsigned short* k_hi = sp + 5 * (size_t)NE_;
    unsigned short* k_lo = sp + 6 * (size_t)NE_;
    unsigned short* k_sg = sp + 7 * (size_t)NE_;
    unsigned short* v_mu = sp + 8 * (size_t)NE_;
    unsigned short* v_sg = sp + 9 * (size_t)NE_;
    unsigned short* v_cb = sp + 10 * (size_t)NE_;
    unsigned short* a_m16 = sp + 11 * (size_t)NE_;
    unsigned short* a_s16 = sp + 12 * (size_t)NE_;
    unsigned short* wt_mu = sp + 13 * (size_t)NE_;
    unsigned short* wt_sg = wt_mu + 4 * (size_t)WE;
    float* fstats = (float*)(wt_sg + 4 * (size_t)WE);
    float* xx = fstats;
    float* ss = fstats + NROWS;
    float* xx2 = fstats + 2 * NROWS;
    float* ss2 = fstats + 3 * NROWS;

    zero_kernel<<<1, 64, 0, stream>>>(out_kl);
    kl_kernel<<<64, 256, 0, stream>>>(wq_mu, wq_sg, out_kl);
    kl_kernel<<<64, 256, 0, stream>>>(wk_mu, wk_sg, out_kl);
    kl_kernel<<<64, 256, 0, stream>>>(wv_mu, wv_sg, out_kl);
    kl_kernel<<<64, 256, 0, stream>>>(wo_mu, wo_sg, out_kl);

    pack_in_kernel<<<NE_ / 2048, 256, 0, stream>>>(mu_in, sg_in, in_m16, in_s16);
    packT_kernel<<<dim3(24, 24, 4), 256, 0, stream>>>(wq_mu, wk_mu, wv_mu, wo_mu, wt_mu, wt_sg);
    rowstats_kernel<<<NROWS / 4, 256, 0, stream>>>(mu_in, sg_in, xx, ss);

    linear_qkv_kernel<<<dim3(NROWS / 64, E / 128, 3), 512, 0, stream>>>(
        in_m16, in_s16, wt_mu, wt_sg, wq_sg, wk_sg, wv_sg, xx, ss,
        q_hi, q_lo, q_sg, k_hi, k_lo, k_sg, v_mu, v_sg, v_cb);

    attn3_kernel<<<Bsz * H * (S / 32), 512, 0, stream>>>(q_hi, q_lo, q_sg, k_hi, k_lo, k_sg,
                                                         v_mu, v_sg, v_cb, a_m16, a_s16);

    rowstats16_kernel<<<NROWS / 4, 256, 0, stream>>>(a_m16, a_s16, xx2, ss2);
    linear_out_kernel<<<dim3(NROWS / 64, E / 128), 512, 0, stream>>>(
        a_m16, a_s16, wt_mu + 3 * (size_t)WE, wt_sg + 3 * (size_t)WE,
        wo_sg, xx2, ss2, out_mu, out_sg);
}